// Round 1
// baseline (948.525 us; speedup 1.0000x reference)
//
#include <hip/hip_runtime.h>

#define NN 100000
#define NE 640000
#define HD 128
#define NG 512
#define NC 6
#define EPSV 1e-5f

// ---------------- counting / CSR build ----------------
__global__ void k_count(const int* __restrict__ dst, int* __restrict__ cnt) {
    int e = blockIdx.x * blockDim.x + threadIdx.x;
    if (e < NE) atomicAdd(&cnt[dst[e]], 1);
}

__global__ void k_scan1(const int* __restrict__ cnt, int* __restrict__ excl,
                        int* __restrict__ bsum, int n) {
    __shared__ int sh[256];
    int i = blockIdx.x * 256 + threadIdx.x;
    int v = (i < n) ? cnt[i] : 0;
    sh[threadIdx.x] = v;
    __syncthreads();
    for (int off = 1; off < 256; off <<= 1) {
        int t = (threadIdx.x >= off) ? sh[threadIdx.x - off] : 0;
        __syncthreads();
        sh[threadIdx.x] += t;
        __syncthreads();
    }
    if (i < n) excl[i] = sh[threadIdx.x] - v;
    if (threadIdx.x == 255) bsum[blockIdx.x] = sh[255];
}

__global__ void k_scan2(int* bsum, int nb) {
    __shared__ int sh[512];
    int t = threadIdx.x;
    sh[t] = (t < nb) ? bsum[t] : 0;
    __syncthreads();
    for (int off = 1; off < 512; off <<= 1) {
        int v = (t >= off) ? sh[t - off] : 0;
        __syncthreads();
        sh[t] += v;
        __syncthreads();
    }
    if (t < nb) bsum[t] = sh[t];
}

__global__ void k_scan3(const int* __restrict__ excl, const int* __restrict__ bsum,
                        int* __restrict__ row_off, int n) {
    int i = blockIdx.x * 256 + threadIdx.x;
    if (i < n) row_off[i] = excl[i] + (blockIdx.x ? bsum[blockIdx.x - 1] : 0);
    if (i == 0) row_off[n] = NE;
}

__global__ void k_fill(const int* __restrict__ src, const int* __restrict__ dst,
                       const int* __restrict__ row_off, int* __restrict__ fillp,
                       int* __restrict__ csr) {
    int e = blockIdx.x * blockDim.x + threadIdx.x;
    if (e < NE) {
        int d = dst[e];
        int p = atomicAdd(&fillp[d], 1);
        csr[row_off[d] + p] = src[e];
    }
}

// ---------------- mean aggregation (gather) ----------------
__global__ __launch_bounds__(256) void k_gather(const float* __restrict__ X,
                                                const int* __restrict__ row_off,
                                                const int* __restrict__ csr,
                                                float* __restrict__ out) {
    int node = (blockIdx.x * blockDim.x + threadIdx.x) >> 6;
    int lane = threadIdx.x & 63;
    if (node >= NN) return;
    int beg = row_off[node], end = row_off[node + 1];
    float ax = 0.f, ay = 0.f;
    for (int j = beg; j < end; ++j) {
        int s = csr[j];
        float2 v = *reinterpret_cast<const float2*>(X + (size_t)s * HD + lane * 2);
        ax += v.x; ay += v.y;
    }
    float inv = 1.f / fmaxf((float)(end - beg), 1.f);
    float2 o; o.x = ax * inv; o.y = ay * inv;
    *reinterpret_cast<float2*>(out + (size_t)node * HD + lane * 2) = o;
}

// ---------------- dual-source GEMM: out = act(A1@W1 [+ A2@W2] + bias) ----------------
// M x 128 times 128 x 128. One wave owns 8 rows x 128 cols. A loads are
// wave-uniform -> scalar loads; W streams coalesced through L1.
template<int ACT>  // 0=none 1=relu 2=tanh
__global__ __launch_bounds__(256) void gemm_dual(
    const float* A1, const float* __restrict__ W1,
    const float* A2, const float* __restrict__ W2,
    const float* __restrict__ bias, float* out, int M)
{
    const int tid = threadIdx.x;
    const int w = __builtin_amdgcn_readfirstlane(tid >> 6);
    const int lane = tid & 63;
    const int r0 = blockIdx.x * 32 + w * 8;
    if (r0 >= M) return;
    const int c0 = lane, c1 = lane + 64;

    float acc0[8], acc1[8];
    const float b0 = bias[c0], b1 = bias[c1];
#pragma unroll
    for (int r = 0; r < 8; ++r) { acc0[r] = b0; acc1[r] = b1; }

    const float* Ap = A1 + (size_t)r0 * HD;
    const float* Wp = W1;
    for (int s = 0; s < 2; ++s) {
        for (int k4 = 0; k4 < HD / 4; ++k4) {
            float4 a[8];
#pragma unroll
            for (int r = 0; r < 8; ++r)
                a[r] = *reinterpret_cast<const float4*>(Ap + r * HD + k4 * 4);
#pragma unroll
            for (int j = 0; j < 4; ++j) {
                const int k = k4 * 4 + j;
                const float w0 = Wp[k * HD + c0];
                const float w1 = Wp[k * HD + c1];
#pragma unroll
                for (int r = 0; r < 8; ++r) {
                    const float av = (j == 0) ? a[r].x : (j == 1) ? a[r].y
                                   : (j == 2) ? a[r].z : a[r].w;
                    acc0[r] = fmaf(av, w0, acc0[r]);
                    acc1[r] = fmaf(av, w1, acc1[r]);
                }
            }
        }
        if (!A2) break;
        Ap = A2 + (size_t)r0 * HD;
        Wp = W2;
    }
#pragma unroll
    for (int r = 0; r < 8; ++r) {
        float v0 = acc0[r], v1 = acc1[r];
        if (ACT == 1) { v0 = fmaxf(v0, 0.f); v1 = fmaxf(v1, 0.f); }
        if (ACT == 2) { v0 = tanhf(v0); v1 = tanhf(v1); }
        out[(size_t)(r0 + r) * HD + c0] = v0;
        out[(size_t)(r0 + r) * HD + c1] = v1;
    }
}

// ---------------- attention a = softmax(t @ Wc2 + bc2) ----------------
__global__ __launch_bounds__(256) void k_attn(const float* __restrict__ t,
                                              const float* __restrict__ Wc2,
                                              const float* __restrict__ bc2,
                                              float* __restrict__ a2) {
    int node = (blockIdx.x * blockDim.x + threadIdx.x) >> 6;
    int lane = threadIdx.x & 63;
    if (node >= NN) return;
    float2 tv = *reinterpret_cast<const float2*>(t + (size_t)node * HD + lane * 2);
    float4 wv = *reinterpret_cast<const float4*>(Wc2 + lane * 4);
    float p0 = tv.x * wv.x + tv.y * wv.z;
    float p1 = tv.x * wv.y + tv.y * wv.w;
#pragma unroll
    for (int off = 32; off; off >>= 1) {
        p0 += __shfl_xor(p0, off, 64);
        p1 += __shfl_xor(p1, off, 64);
    }
    if (lane == 0) {
        float u0 = p0 + bc2[0], u1 = p1 + bc2[1];
        float m = fmaxf(u0, u1);
        float e0 = expf(u0 - m), e1 = expf(u1 - m);
        float inv = 1.f / (e0 + e1);
        a2[node * 2] = e0 * inv;
        a2[node * 2 + 1] = e1 * inv;
    }
}

// ---------------- pos: per-graph sum of a0 * h ----------------
__global__ void k_pos(const float* __restrict__ h, const float* __restrict__ a2,
                      const int* __restrict__ batch, float* __restrict__ pos_out) {
    int g = blockIdx.x;
    int f = threadIdx.x;  // 128 threads
    int lo = 0, hi = NN;
    while (lo < hi) { int m = (lo + hi) >> 1; if (batch[m] < g) lo = m + 1; else hi = m; }
    int beg = lo;
    hi = NN;
    while (lo < hi) { int m = (lo + hi) >> 1; if (batch[m] < g + 1) lo = m + 1; else hi = m; }
    int end = lo;
    float acc = 0.f;
    for (int i = beg; i < end; ++i)
        acc += a2[i * 2] * h[(size_t)i * HD + f];
    pos_out[g * HD + f] = acc;
}

// ---------------- column sums for graph_emb ----------------
__global__ void k_colsum(const float* __restrict__ h, float* __restrict__ csum) {
    int f = threadIdx.x;  // 128
    float acc = 0.f;
    for (int r = blockIdx.x; r < NN; r += gridDim.x)
        acc += h[(size_t)r * HD + f];
    atomicAdd(&csum[f], acc);
}

__global__ void k_gemb(const float* __restrict__ csum, float* __restrict__ out) {
    int i = blockIdx.x * 256 + threadIdx.x;  // 65536
    out[i] = csum[i & 127] * (1.f / (float)NN);
}

// ---------------- new_adj accumulation ----------------
__global__ void k_adj(const int* __restrict__ src, const int* __restrict__ dst,
                      const int* __restrict__ batch, const float* __restrict__ a2,
                      float* __restrict__ adj) {
    int e = blockIdx.x * blockDim.x + threadIdx.x;
    if (e >= NE) return;
    int s = src[e], d = dst[e];
    int bs = batch[s], bd = batch[d];
    if (bs != bd) return;
    float a0s = a2[2 * s], a1s = a2[2 * s + 1];
    float a0d = a2[2 * d], a1d = a2[2 * d + 1];
    float* A = adj + bs * 4;
    atomicAdd(A + 0, a0s * a0d);
    atomicAdd(A + 1, a0s * a1d);
    atomicAdd(A + 2, a1s * a0d);
    atomicAdd(A + 3, a1s * a1d);
}

__global__ void k_penalty(const float* __restrict__ adj, float* __restrict__ out) {
    __shared__ float sh[512];
    int g = threadIdx.x;  // 512 threads, G=512
    float x0 = adj[g * 4], x1 = adj[g * 4 + 1], x2 = adj[g * 4 + 2], x3 = adj[g * 4 + 3];
    float l0 = fabsf(x0) + fabsf(x1);
    float l1 = fabsf(x2) + fabsf(x3);
    float d0 = x0 / fmaxf(l0, EPSV);
    float d1 = x3 / fmaxf(l1, EPSV);
    sh[g] = 0.5f * ((d0 - 1.f) * (d0 - 1.f) + (d1 - 1.f) * (d1 - 1.f));
    __syncthreads();
    for (int off = 256; off >= 1; off >>= 1) {
        if (g < off) sh[g] += sh[g + off];
        __syncthreads();
    }
    if (g == 0) out[0] = sh[0] * (1.f / (float)NG);
}

// ---------------- final head: logits + log_softmax ----------------
__global__ void k_head(const float* __restrict__ z, const float* __restrict__ Wl2,
                       const float* __restrict__ bl2, float* __restrict__ out0) {
    int g = blockIdx.x * blockDim.x + threadIdx.x;
    if (g >= NG) return;
    float l[NC];
#pragma unroll
    for (int c = 0; c < NC; ++c) l[c] = bl2[c];
    for (int k = 0; k < HD; ++k) {
        float zv = z[(size_t)g * HD + k];
#pragma unroll
        for (int c = 0; c < NC; ++c) l[c] = fmaf(zv, Wl2[k * NC + c], l[c]);
    }
    float m = l[0];
#pragma unroll
    for (int c = 1; c < NC; ++c) m = fmaxf(m, l[c]);
    float sum = 0.f;
#pragma unroll
    for (int c = 0; c < NC; ++c) sum += expf(l[c] - m);
    float lse = m + logf(sum);
#pragma unroll
    for (int c = 0; c < NC; ++c) out0[g * NC + c] = l[c] - lse;
}

extern "C" void kernel_launch(void* const* d_in, const int* in_sizes, int n_in,
                              void* d_out, int out_size, void* d_ws, size_t ws_size,
                              hipStream_t stream) {
    const float* x   = (const float*)d_in[0];
    const int*   ei  = (const int*)d_in[1];
    const int*   src = ei;
    const int*   dst = ei + NE;
    const int*   batch = (const int*)d_in[2];
    const float* W1l = (const float*)d_in[4];
    const float* b1l = (const float*)d_in[5];
    const float* W1r = (const float*)d_in[6];
    const float* W2l = (const float*)d_in[7];
    const float* b2l = (const float*)d_in[8];
    const float* W2r = (const float*)d_in[9];
    const float* Wc1 = (const float*)d_in[10];
    const float* bc1 = (const float*)d_in[11];
    const float* Wc2 = (const float*)d_in[12];
    const float* bc2 = (const float*)d_in[13];
    const float* Wl1 = (const float*)d_in[14];
    const float* bl1 = (const float*)d_in[15];
    const float* Wl2 = (const float*)d_in[16];
    const float* bl2 = (const float*)d_in[17];

    char* ws = (char*)d_ws;
    const size_t BIG = (size_t)NN * HD * 4;  // 51,200,000
    float* bufA    = (float*)(ws);
    float* bufB    = (float*)(ws + BIG);
    int*   cnt     = (int*)(ws + 2 * BIG);                    // N ints
    int*   excl    = (int*)(ws + 2 * BIG + 400000);
    int*   row_off = (int*)(ws + 2 * BIG + 800000);           // N+1
    int*   fillp   = (int*)(ws + 2 * BIG + 1200128);
    int*   csr     = (int*)(ws + 2 * BIG + 1600128);          // E ints
    int*   bsum    = (int*)(ws + 2 * BIG + 4160128);          // 1024 ints
    float* a2      = (float*)(ws + 2 * BIG + 4164224);        // N*2
    float* adj     = (float*)(ws + 2 * BIG + 4964224);        // G*4
    float* csum    = (float*)(ws + 2 * BIG + 4972416);        // 128
    float* zbuf    = (float*)(ws + 2 * BIG + 4972928);        // G*128

    float* out0 = (float*)d_out;     // 512*6
    float* pos  = out0 + NG * NC;    // 512*128
    float* gemb = pos + NG * HD;     // 512*128
    float* pen  = gemb + NG * HD;    // 1

    hipMemsetAsync(cnt, 0, NN * 4, stream);
    hipMemsetAsync(fillp, 0, NN * 4, stream);
    hipMemsetAsync(adj, 0, NG * 4 * 4, stream);
    hipMemsetAsync(csum, 0, HD * 4, stream);

    // CSR build (by dst)
    k_count<<<NE / 256, 256, 0, stream>>>(dst, cnt);
    k_scan1<<<391, 256, 0, stream>>>(cnt, excl, bsum, NN);
    k_scan2<<<1, 512, 0, stream>>>(bsum, 391);
    k_scan3<<<391, 256, 0, stream>>>(excl, bsum, row_off, NN);
    k_fill<<<NE / 256, 256, 0, stream>>>(src, dst, row_off, fillp, csr);

    // Layer 1: agg1 = mean-neigh(x); h1 = relu(agg1@W1l + x@W1r + b1l)
    k_gather<<<NN / 4, 256, 0, stream>>>(x, row_off, csr, bufB);
    gemm_dual<1><<<NN / 32, 256, 0, stream>>>(bufB, W1l, x, W1r, b1l, bufA, NN);
    // Layer 2: agg2 = mean-neigh(h1); h2 = relu(agg2@W2l + h1@W2r + b2l)
    k_gather<<<NN / 4, 256, 0, stream>>>(bufA, row_off, csr, bufB);
    gemm_dual<1><<<NN / 32, 256, 0, stream>>>(bufB, W2l, bufA, W2r, b2l, bufB, NN);
    // t = tanh(h2@Wc1 + bc1)
    gemm_dual<2><<<NN / 32, 256, 0, stream>>>(bufB, Wc1, nullptr, nullptr, bc1, bufA, NN);
    // a = softmax(t@Wc2 + bc2)
    k_attn<<<NN / 4, 256, 0, stream>>>(bufA, Wc2, bc2, a2);
    // pos (graph feature, channel 0 only is used)
    k_pos<<<NG, 128, 0, stream>>>(bufB, a2, batch, pos);
    // graph_emb = broadcast(mean(h2, axis=0))
    k_colsum<<<512, 128, 0, stream>>>(bufB, csum);
    k_gemb<<<NG * HD / 256, 256, 0, stream>>>(csum, gemb);
    // new_adj + penalty
    k_adj<<<NE / 256, 256, 0, stream>>>(src, dst, batch, a2, adj);
    k_penalty<<<1, 512, 0, stream>>>(adj, pen);
    // head: z = relu(pos@Wl1 + bl1); out0 = log_softmax(z@Wl2 + bl2)
    gemm_dual<1><<<NG / 32, 256, 0, stream>>>(pos, Wl1, nullptr, nullptr, bl1, zbuf, NG);
    k_head<<<2, 256, 0, stream>>>(zbuf, Wl2, bl2, out0);
}

// Round 2
// 587.429 us; speedup vs baseline: 1.6147x; 1.6147x over previous
//
#include <hip/hip_runtime.h>

#define NN 100000
#define NE 640000
#define HD 128
#define NG 512
#define NC 6
#define EPSV 1e-5f

typedef __bf16 bf16_t;
typedef bf16_t bf16x8 __attribute__((ext_vector_type(8)));
typedef float f32x4 __attribute__((ext_vector_type(4)));

__device__ __forceinline__ float b2f(unsigned int u16) {
    return __builtin_bit_cast(float, u16 << 16);
}
__device__ __forceinline__ unsigned short f2b(float f) {
    unsigned int u = __builtin_bit_cast(unsigned int, f);
    unsigned int r = (u + 0x7fffu + ((u >> 16) & 1u)) >> 16;
    return (unsigned short)r;
}

// ---------------- fp32 -> bf16 conversion (x) ----------------
__global__ __launch_bounds__(256) void k_cvt(const float* __restrict__ in,
                                             unsigned short* __restrict__ out, int n8) {
    int i = blockIdx.x * 256 + threadIdx.x;
    if (i >= n8) return;
    float4 v0 = reinterpret_cast<const float4*>(in)[i * 2];
    float4 v1 = reinterpret_cast<const float4*>(in)[i * 2 + 1];
    unsigned short u[8] = {f2b(v0.x), f2b(v0.y), f2b(v0.z), f2b(v0.w),
                           f2b(v1.x), f2b(v1.y), f2b(v1.z), f2b(v1.w)};
    reinterpret_cast<uint4*>(out)[i] = *reinterpret_cast<uint4*>(u);
}

// ---------------- weight transpose + convert: Wt[n][k] = bf16(W[k][n]) ----------------
__global__ __launch_bounds__(256) void k_prepw(const float* __restrict__ W,
                                               unsigned short* __restrict__ Wt) {
    int i = blockIdx.x * 256 + threadIdx.x;  // 16384
    int k = i >> 7, n = i & 127;
    Wt[n * HD + k] = f2b(W[k * HD + n]);
}

// ---------------- counting / CSR build ----------------
__global__ void k_count(const int* __restrict__ dst, int* __restrict__ cnt) {
    int e = blockIdx.x * blockDim.x + threadIdx.x;
    if (e < NE) atomicAdd(&cnt[dst[e]], 1);
}

__global__ void k_scan1(const int* __restrict__ cnt, int* __restrict__ excl,
                        int* __restrict__ bsum, int n) {
    __shared__ int sh[256];
    int i = blockIdx.x * 256 + threadIdx.x;
    int v = (i < n) ? cnt[i] : 0;
    sh[threadIdx.x] = v;
    __syncthreads();
    for (int off = 1; off < 256; off <<= 1) {
        int t = (threadIdx.x >= off) ? sh[threadIdx.x - off] : 0;
        __syncthreads();
        sh[threadIdx.x] += t;
        __syncthreads();
    }
    if (i < n) excl[i] = sh[threadIdx.x] - v;
    if (threadIdx.x == 255) bsum[blockIdx.x] = sh[255];
}

__global__ void k_scan2(int* bsum, int nb) {
    __shared__ int sh[512];
    int t = threadIdx.x;
    sh[t] = (t < nb) ? bsum[t] : 0;
    __syncthreads();
    for (int off = 1; off < 512; off <<= 1) {
        int v = (t >= off) ? sh[t - off] : 0;
        __syncthreads();
        sh[t] += v;
        __syncthreads();
    }
    if (t < nb) bsum[t] = sh[t];
}

__global__ void k_scan3(const int* __restrict__ excl, const int* __restrict__ bsum,
                        int* __restrict__ row_off, int n) {
    int i = blockIdx.x * 256 + threadIdx.x;
    if (i < n) row_off[i] = excl[i] + (blockIdx.x ? bsum[blockIdx.x - 1] : 0);
    if (i == 0) row_off[n] = NE;
}

__global__ void k_fill(const int* __restrict__ src, const int* __restrict__ dst,
                       const int* __restrict__ row_off, int* __restrict__ fillp,
                       int* __restrict__ csr) {
    int e = blockIdx.x * blockDim.x + threadIdx.x;
    if (e < NE) {
        int d = dst[e];
        int p = atomicAdd(&fillp[d], 1);
        csr[row_off[d] + p] = src[e];
    }
}

// ---------------- mean aggregation (gather, bf16 in/out, fp32 accum) ----------------
__global__ __launch_bounds__(256) void k_gather_b(const unsigned short* __restrict__ X,
                                                  const int* __restrict__ row_off,
                                                  const int* __restrict__ csr,
                                                  unsigned short* __restrict__ out) {
    int node = (blockIdx.x * blockDim.x + threadIdx.x) >> 6;
    int lane = threadIdx.x & 63;
    if (node >= NN) return;
    int beg = row_off[node], end = row_off[node + 1];
    float ax = 0.f, ay = 0.f;
    for (int j = beg; j < end; ++j) {
        int s = csr[j];
        unsigned int v = *reinterpret_cast<const unsigned int*>(X + (size_t)s * HD + lane * 2);
        ax += b2f(v & 0xffffu);
        ay += b2f(v >> 16);
    }
    float inv = 1.f / fmaxf((float)(end - beg), 1.f);
    unsigned int o = (unsigned int)f2b(ax * inv) | ((unsigned int)f2b(ay * inv) << 16);
    *reinterpret_cast<unsigned int*>(out + (size_t)node * HD + lane * 2) = o;
}

// ---------------- MFMA dual-source GEMM: out = act(A1@W1 [+ A2@W2] + bias) ----------------
// Wave owns 16 rows x 128 cols. mfma_f32_16x16x32_bf16.
// A-frag: row=lane&15, k=(lane>>4)*8+j. B-frag from Wt[n][k]: col=lane&15, same k.
// D: col=lane&15, row=(lane>>4)*4+r.
template<int ACT>  // 1=relu 2=tanh
__global__ __launch_bounds__(256) void mfma_dual(
    const unsigned short* __restrict__ A1, const unsigned short* __restrict__ W1t,
    const unsigned short* A2, const unsigned short* W2t,
    const float* __restrict__ bias, unsigned short* __restrict__ out, int M)
{
    const int wid = threadIdx.x >> 6;
    const int lane = threadIdx.x & 63;
    const int r0 = (blockIdx.x * 4 + wid) * 16;
    if (r0 >= M) return;
    const int lrow = lane & 15;
    const int lkg = lane >> 4;

    f32x4 acc[8];
#pragma unroll
    for (int t = 0; t < 8; ++t) {
        float b = bias[t * 16 + lrow];
        acc[t] = (f32x4){b, b, b, b};
    }

    const unsigned short* a_base = A1 + (size_t)(r0 + lrow) * HD + lkg * 8;
    const unsigned short* w_base = W1t + (size_t)lrow * HD + lkg * 8;
    for (int s = 0; s < 2; ++s) {
#pragma unroll
        for (int ks = 0; ks < 4; ++ks) {
            bf16x8 a = *reinterpret_cast<const bf16x8*>(a_base + ks * 32);
#pragma unroll
            for (int t = 0; t < 8; ++t) {
                bf16x8 b = *reinterpret_cast<const bf16x8*>(w_base + (size_t)t * 16 * HD + ks * 32);
                acc[t] = __builtin_amdgcn_mfma_f32_16x16x32_bf16(a, b, acc[t], 0, 0, 0);
            }
        }
        if (!A2) break;
        a_base = A2 + (size_t)(r0 + lrow) * HD + lkg * 8;
        w_base = W2t + (size_t)lrow * HD + lkg * 8;
    }

#pragma unroll
    for (int t = 0; t < 8; ++t)
#pragma unroll
        for (int r = 0; r < 4; ++r) {
            float v = acc[t][r];
            if (ACT == 1) v = fmaxf(v, 0.f);
            if (ACT == 2) v = tanhf(v);
            out[(size_t)(r0 + lkg * 4 + r) * HD + t * 16 + lrow] = f2b(v);
        }
}

// ---------------- attention a = softmax(t @ Wc2 + bc2), t in bf16 ----------------
__global__ __launch_bounds__(256) void k_attn_b(const unsigned short* __restrict__ t,
                                                const float* __restrict__ Wc2,
                                                const float* __restrict__ bc2,
                                                float* __restrict__ a2) {
    int node = (blockIdx.x * blockDim.x + threadIdx.x) >> 6;
    int lane = threadIdx.x & 63;
    if (node >= NN) return;
    unsigned int tv = *reinterpret_cast<const unsigned int*>(t + (size_t)node * HD + lane * 2);
    float t0 = b2f(tv & 0xffffu), t1 = b2f(tv >> 16);
    float4 wv = *reinterpret_cast<const float4*>(Wc2 + lane * 4);
    float p0 = t0 * wv.x + t1 * wv.z;
    float p1 = t0 * wv.y + t1 * wv.w;
#pragma unroll
    for (int off = 32; off; off >>= 1) {
        p0 += __shfl_xor(p0, off, 64);
        p1 += __shfl_xor(p1, off, 64);
    }
    if (lane == 0) {
        float u0 = p0 + bc2[0], u1 = p1 + bc2[1];
        float m = fmaxf(u0, u1);
        float e0 = expf(u0 - m), e1 = expf(u1 - m);
        float inv = 1.f / (e0 + e1);
        a2[node * 2] = e0 * inv;
        a2[node * 2 + 1] = e1 * inv;
    }
}

// ---------------- pos: per-graph sum of a0 * h (h bf16) ----------------
__global__ void k_pos(const unsigned short* __restrict__ h, const float* __restrict__ a2,
                      const int* __restrict__ batch, float* __restrict__ pos_out) {
    int g = blockIdx.x;
    int f = threadIdx.x;  // 128 threads
    int lo = 0, hi = NN;
    while (lo < hi) { int m = (lo + hi) >> 1; if (batch[m] < g) lo = m + 1; else hi = m; }
    int beg = lo;
    hi = NN;
    while (lo < hi) { int m = (lo + hi) >> 1; if (batch[m] < g + 1) lo = m + 1; else hi = m; }
    int end = lo;
    float acc = 0.f;
    for (int i = beg; i < end; ++i)
        acc += a2[i * 2] * b2f(h[(size_t)i * HD + f]);
    pos_out[g * HD + f] = acc;
}

// ---------------- column sums for graph_emb (h bf16) ----------------
__global__ void k_colsum(const unsigned short* __restrict__ h, float* __restrict__ csum) {
    int f = threadIdx.x;  // 128
    float acc = 0.f;
    for (int r = blockIdx.x; r < NN; r += gridDim.x)
        acc += b2f(h[(size_t)r * HD + f]);
    atomicAdd(&csum[f], acc);
}

__global__ void k_gemb(const float* __restrict__ csum, float* __restrict__ out) {
    int i = blockIdx.x * 256 + threadIdx.x;  // 65536
    out[i] = csum[i & 127] * (1.f / (float)NN);
}

// ---------------- new_adj accumulation: LDS-staged atomics ----------------
__global__ __launch_bounds__(256) void k_adj(const int* __restrict__ src, const int* __restrict__ dst,
                                             const int* __restrict__ batch, const float* __restrict__ a2,
                                             float* __restrict__ adj) {
    __shared__ float sh[NG * 4];  // 8 KB
    for (int i = threadIdx.x; i < NG * 4; i += 256) sh[i] = 0.f;
    __syncthreads();
    for (int e = blockIdx.x * 256 + threadIdx.x; e < NE; e += gridDim.x * 256) {
        int s = src[e], d = dst[e];
        int bs = batch[s], bd = batch[d];
        if (bs != bd) continue;
        float a0s = a2[2 * s], a1s = a2[2 * s + 1];
        float a0d = a2[2 * d], a1d = a2[2 * d + 1];
        float* A = sh + bs * 4;
        atomicAdd(A + 0, a0s * a0d);
        atomicAdd(A + 1, a0s * a1d);
        atomicAdd(A + 2, a1s * a0d);
        atomicAdd(A + 3, a1s * a1d);
    }
    __syncthreads();
    for (int i = threadIdx.x; i < NG * 4; i += 256) {
        float v = sh[i];
        if (v != 0.f) atomicAdd(&adj[i], v);
    }
}

__global__ void k_penalty(const float* __restrict__ adj, float* __restrict__ out) {
    __shared__ float sh[512];
    int g = threadIdx.x;  // 512 threads, G=512
    float x0 = adj[g * 4], x1 = adj[g * 4 + 1], x2 = adj[g * 4 + 2], x3 = adj[g * 4 + 3];
    float l0 = fabsf(x0) + fabsf(x1);
    float l1 = fabsf(x2) + fabsf(x3);
    float d0 = x0 / fmaxf(l0, EPSV);
    float d1 = x3 / fmaxf(l1, EPSV);
    sh[g] = 0.5f * ((d0 - 1.f) * (d0 - 1.f) + (d1 - 1.f) * (d1 - 1.f));
    __syncthreads();
    for (int off = 256; off >= 1; off >>= 1) {
        if (g < off) sh[g] += sh[g + off];
        __syncthreads();
    }
    if (g == 0) out[0] = sh[0] * (1.f / (float)NG);
}

// ---------------- fp32 head GEMM (512 rows): out = relu(A@W + b) ----------------
__global__ __launch_bounds__(256) void gemm_head(
    const float* __restrict__ A, const float* __restrict__ W,
    const float* __restrict__ bias, float* __restrict__ out, int M)
{
    const int tid = threadIdx.x;
    const int w = __builtin_amdgcn_readfirstlane(tid >> 6);
    const int lane = tid & 63;
    const int r0 = blockIdx.x * 32 + w * 8;
    if (r0 >= M) return;
    const int c0 = lane, c1 = lane + 64;
    float acc0[8], acc1[8];
    const float b0 = bias[c0], b1 = bias[c1];
#pragma unroll
    for (int r = 0; r < 8; ++r) { acc0[r] = b0; acc1[r] = b1; }
    const float* Ap = A + (size_t)r0 * HD;
    for (int k4 = 0; k4 < HD / 4; ++k4) {
        float4 a[8];
#pragma unroll
        for (int r = 0; r < 8; ++r)
            a[r] = *reinterpret_cast<const float4*>(Ap + r * HD + k4 * 4);
#pragma unroll
        for (int j = 0; j < 4; ++j) {
            const int k = k4 * 4 + j;
            const float w0 = W[k * HD + c0];
            const float w1 = W[k * HD + c1];
#pragma unroll
            for (int r = 0; r < 8; ++r) {
                const float av = (j == 0) ? a[r].x : (j == 1) ? a[r].y
                               : (j == 2) ? a[r].z : a[r].w;
                acc0[r] = fmaf(av, w0, acc0[r]);
                acc1[r] = fmaf(av, w1, acc1[r]);
            }
        }
    }
#pragma unroll
    for (int r = 0; r < 8; ++r) {
        out[(size_t)(r0 + r) * HD + c0] = fmaxf(acc0[r], 0.f);
        out[(size_t)(r0 + r) * HD + c1] = fmaxf(acc1[r], 0.f);
    }
}

// ---------------- final head: logits + log_softmax ----------------
__global__ void k_head(const float* __restrict__ z, const float* __restrict__ Wl2,
                       const float* __restrict__ bl2, float* __restrict__ out0) {
    int g = blockIdx.x * blockDim.x + threadIdx.x;
    if (g >= NG) return;
    float l[NC];
#pragma unroll
    for (int c = 0; c < NC; ++c) l[c] = bl2[c];
    for (int k = 0; k < HD; ++k) {
        float zv = z[(size_t)g * HD + k];
#pragma unroll
        for (int c = 0; c < NC; ++c) l[c] = fmaf(zv, Wl2[k * NC + c], l[c]);
    }
    float m = l[0];
#pragma unroll
    for (int c = 1; c < NC; ++c) m = fmaxf(m, l[c]);
    float sum = 0.f;
#pragma unroll
    for (int c = 0; c < NC; ++c) sum += expf(l[c] - m);
    float lse = m + logf(sum);
#pragma unroll
    for (int c = 0; c < NC; ++c) out0[g * NC + c] = l[c] - lse;
}

extern "C" void kernel_launch(void* const* d_in, const int* in_sizes, int n_in,
                              void* d_out, int out_size, void* d_ws, size_t ws_size,
                              hipStream_t stream) {
    const float* x   = (const float*)d_in[0];
    const int*   ei  = (const int*)d_in[1];
    const int*   src = ei;
    const int*   dst = ei + NE;
    const int*   batch = (const int*)d_in[2];
    const float* W1l = (const float*)d_in[4];
    const float* b1l = (const float*)d_in[5];
    const float* W1r = (const float*)d_in[6];
    const float* W2l = (const float*)d_in[7];
    const float* b2l = (const float*)d_in[8];
    const float* W2r = (const float*)d_in[9];
    const float* Wc1 = (const float*)d_in[10];
    const float* bc1 = (const float*)d_in[11];
    const float* Wc2 = (const float*)d_in[12];
    const float* bc2 = (const float*)d_in[13];
    const float* Wl1 = (const float*)d_in[14];
    const float* bl1 = (const float*)d_in[15];
    const float* Wl2 = (const float*)d_in[16];
    const float* bl2 = (const float*)d_in[17];

    char* ws = (char*)d_ws;
    const size_t BB = (size_t)NN * HD * 2;  // 25,600,000 (bf16 buffer)
    unsigned short* xb   = (unsigned short*)(ws);
    unsigned short* bufA = (unsigned short*)(ws + BB);
    unsigned short* bufB = (unsigned short*)(ws + 2 * BB);
    size_t O = 3 * BB;  // 76,800,000
    int*   cnt     = (int*)(ws + O);
    int*   excl    = (int*)(ws + O + 400000);
    int*   row_off = (int*)(ws + O + 800000);
    int*   fillp   = (int*)(ws + O + 1200064);
    int*   csr     = (int*)(ws + O + 1600064);
    int*   bsum    = (int*)(ws + O + 4160064);
    float* a2      = (float*)(ws + O + 4164160);
    float* adj     = (float*)(ws + O + 4964160);
    float* csum    = (float*)(ws + O + 4972352);
    float* zbuf    = (float*)(ws + O + 4972864);
    unsigned short* w1lt = (unsigned short*)(ws + O + 5235008);
    unsigned short* w1rt = w1lt + 16384;
    unsigned short* w2lt = w1rt + 16384;
    unsigned short* w2rt = w2lt + 16384;
    unsigned short* wc1t = w2rt + 16384;

    float* out0 = (float*)d_out;     // 512*6
    float* pos  = out0 + NG * NC;    // 512*128
    float* gemb = pos + NG * HD;     // 512*128
    float* pen  = gemb + NG * HD;    // 1

    hipMemsetAsync(cnt, 0, NN * 4, stream);
    hipMemsetAsync(fillp, 0, NN * 4, stream);
    hipMemsetAsync(adj, 0, NG * 4 * 4, stream);
    hipMemsetAsync(csum, 0, HD * 4, stream);

    // conversions
    k_cvt<<<6250, 256, 0, stream>>>(x, xb, NN * HD / 8);
    k_prepw<<<64, 256, 0, stream>>>(W1l, w1lt);
    k_prepw<<<64, 256, 0, stream>>>(W1r, w1rt);
    k_prepw<<<64, 256, 0, stream>>>(W2l, w2lt);
    k_prepw<<<64, 256, 0, stream>>>(W2r, w2rt);
    k_prepw<<<64, 256, 0, stream>>>(Wc1, wc1t);

    // CSR build (by dst)
    k_count<<<NE / 256, 256, 0, stream>>>(dst, cnt);
    k_scan1<<<391, 256, 0, stream>>>(cnt, excl, bsum, NN);
    k_scan2<<<1, 512, 0, stream>>>(bsum, 391);
    k_scan3<<<391, 256, 0, stream>>>(excl, bsum, row_off, NN);
    k_fill<<<NE / 256, 256, 0, stream>>>(src, dst, row_off, fillp, csr);

    const int GEMM_GRID = (NN / 16 + 3) / 4;  // 1563
    // Layer 1: h1 = relu(mean@W1l + xb@W1r + b1l) -> bufB
    k_gather_b<<<NN / 4, 256, 0, stream>>>(xb, row_off, csr, bufA);
    mfma_dual<1><<<GEMM_GRID, 256, 0, stream>>>(bufA, w1lt, xb, w1rt, b1l, bufB, NN);
    // Layer 2: h2 = relu(mean@W2l + h1@W2r + b2l) -> xb (x no longer needed)
    k_gather_b<<<NN / 4, 256, 0, stream>>>(bufB, row_off, csr, bufA);
    mfma_dual<1><<<GEMM_GRID, 256, 0, stream>>>(bufA, w2lt, bufB, w2rt, b2l, xb, NN);
    // t = tanh(h2@Wc1 + bc1) -> bufB
    mfma_dual<2><<<GEMM_GRID, 256, 0, stream>>>(xb, wc1t, nullptr, nullptr, bc1, bufB, NN);
    // a = softmax(t@Wc2 + bc2)
    k_attn_b<<<NN / 4, 256, 0, stream>>>(bufB, Wc2, bc2, a2);
    // pos
    k_pos<<<NG, 128, 0, stream>>>(xb, a2, batch, pos);
    // graph_emb
    k_colsum<<<512, 128, 0, stream>>>(xb, csum);
    k_gemb<<<NG * HD / 256, 256, 0, stream>>>(csum, gemb);
    // new_adj + penalty
    k_adj<<<120, 256, 0, stream>>>(src, dst, batch, a2, adj);
    k_penalty<<<1, 512, 0, stream>>>(adj, pen);
    // head
    gemm_head<<<NG / 32, 256, 0, stream>>>(pos, Wl1, bl1, zbuf, NG);
    k_head<<<2, 256, 0, stream>>>(zbuf, Wl2, bl2, out0);
}

// Round 3
// 494.574 us; speedup vs baseline: 1.9179x; 1.1877x over previous
//
#include <hip/hip_runtime.h>

#define NN 100000
#define NE 640000
#define HD 128
#define NG 512
#define NC 6
#define EPSV 1e-5f

typedef __bf16 bf16_t;
typedef bf16_t bf16x8 __attribute__((ext_vector_type(8)));
typedef float f32x4 __attribute__((ext_vector_type(4)));

__device__ __forceinline__ float b2f(unsigned int u16) {
    return __builtin_bit_cast(float, u16 << 16);
}
__device__ __forceinline__ unsigned short f2b(float f) {
    unsigned int u = __builtin_bit_cast(unsigned int, f);
    unsigned int r = (u + 0x7fffu + ((u >> 16) & 1u)) >> 16;
    return (unsigned short)r;
}

// ---------------- fp32 -> bf16 conversion (x) ----------------
__global__ __launch_bounds__(256) void k_cvt(const float* __restrict__ in,
                                             unsigned short* __restrict__ out, int n8) {
    int i = blockIdx.x * 256 + threadIdx.x;
    if (i >= n8) return;
    float4 v0 = reinterpret_cast<const float4*>(in)[i * 2];
    float4 v1 = reinterpret_cast<const float4*>(in)[i * 2 + 1];
    unsigned short u[8] = {f2b(v0.x), f2b(v0.y), f2b(v0.z), f2b(v0.w),
                           f2b(v1.x), f2b(v1.y), f2b(v1.z), f2b(v1.w)};
    reinterpret_cast<uint4*>(out)[i] = *reinterpret_cast<uint4*>(u);
}

// ---------------- weight transpose + convert: Wt[n][k] = bf16(W[k][n]) ----------------
__global__ __launch_bounds__(256) void k_prepw(const float* __restrict__ W,
                                               unsigned short* __restrict__ Wt) {
    int i = blockIdx.x * 256 + threadIdx.x;  // 16384
    int k = i >> 7, n = i & 127;
    Wt[n * HD + k] = f2b(W[k * HD + n]);
}

// ---------------- counting / CSR build ----------------
__global__ void k_count(const int* __restrict__ dst, int* __restrict__ cnt) {
    int e = blockIdx.x * blockDim.x + threadIdx.x;
    if (e < NE) atomicAdd(&cnt[dst[e]], 1);
}

__global__ void k_scan1(const int* __restrict__ cnt, int* __restrict__ excl,
                        int* __restrict__ bsum, int n) {
    __shared__ int sh[256];
    int i = blockIdx.x * 256 + threadIdx.x;
    int v = (i < n) ? cnt[i] : 0;
    sh[threadIdx.x] = v;
    __syncthreads();
    for (int off = 1; off < 256; off <<= 1) {
        int t = (threadIdx.x >= off) ? sh[threadIdx.x - off] : 0;
        __syncthreads();
        sh[threadIdx.x] += t;
        __syncthreads();
    }
    if (i < n) excl[i] = sh[threadIdx.x] - v;
    if (threadIdx.x == 255) bsum[blockIdx.x] = sh[255];
}

__global__ void k_scan2(int* bsum, int nb) {
    __shared__ int sh[512];
    int t = threadIdx.x;
    sh[t] = (t < nb) ? bsum[t] : 0;
    __syncthreads();
    for (int off = 1; off < 512; off <<= 1) {
        int v = (t >= off) ? sh[t - off] : 0;
        __syncthreads();
        sh[t] += v;
        __syncthreads();
    }
    if (t < nb) bsum[t] = sh[t];
}

__global__ void k_scan3(const int* __restrict__ excl, const int* __restrict__ bsum,
                        int* __restrict__ row_off, int n) {
    int i = blockIdx.x * 256 + threadIdx.x;
    if (i < n) row_off[i] = excl[i] + (blockIdx.x ? bsum[blockIdx.x - 1] : 0);
    if (i == 0) row_off[n] = NE;
}

__global__ void k_fill(const int* __restrict__ src, const int* __restrict__ dst,
                       const int* __restrict__ row_off, int* __restrict__ fillp,
                       int* __restrict__ csr) {
    int e = blockIdx.x * blockDim.x + threadIdx.x;
    if (e < NE) {
        int d = dst[e];
        int p = atomicAdd(&fillp[d], 1);
        csr[row_off[d] + p] = src[e];
    }
}

// ---------------- mean aggregation (gather, bf16 in/out, fp32 accum) ----------------
__global__ __launch_bounds__(256) void k_gather_b(const unsigned short* __restrict__ X,
                                                  const int* __restrict__ row_off,
                                                  const int* __restrict__ csr,
                                                  unsigned short* __restrict__ out) {
    int node = (blockIdx.x * blockDim.x + threadIdx.x) >> 6;
    int lane = threadIdx.x & 63;
    if (node >= NN) return;
    int beg = row_off[node], end = row_off[node + 1];
    float ax = 0.f, ay = 0.f;
    for (int j = beg; j < end; ++j) {
        int s = csr[j];
        unsigned int v = *reinterpret_cast<const unsigned int*>(X + (size_t)s * HD + lane * 2);
        ax += b2f(v & 0xffffu);
        ay += b2f(v >> 16);
    }
    float inv = 1.f / fmaxf((float)(end - beg), 1.f);
    unsigned int o = (unsigned int)f2b(ax * inv) | ((unsigned int)f2b(ay * inv) << 16);
    *reinterpret_cast<unsigned int*>(out + (size_t)node * HD + lane * 2) = o;
}

// ---------------- MFMA dual-source GEMM: out = relu(A1@W1 + A2@W2 + bias) ----------------
__global__ __launch_bounds__(256) void mfma_dual(
    const unsigned short* __restrict__ A1, const unsigned short* __restrict__ W1t,
    const unsigned short* __restrict__ A2, const unsigned short* __restrict__ W2t,
    const float* __restrict__ bias, unsigned short* __restrict__ out, int M)
{
    const int wid = threadIdx.x >> 6;
    const int lane = threadIdx.x & 63;
    const int r0 = (blockIdx.x * 4 + wid) * 16;
    if (r0 >= M) return;
    const int lrow = lane & 15;
    const int lkg = lane >> 4;

    f32x4 acc[8];
#pragma unroll
    for (int t = 0; t < 8; ++t) {
        float b = bias[t * 16 + lrow];
        acc[t] = (f32x4){b, b, b, b};
    }

    const unsigned short* a_base = A1 + (size_t)(r0 + lrow) * HD + lkg * 8;
    const unsigned short* w_base = W1t + (size_t)lrow * HD + lkg * 8;
    for (int s = 0; s < 2; ++s) {
#pragma unroll
        for (int ks = 0; ks < 4; ++ks) {
            bf16x8 a = *reinterpret_cast<const bf16x8*>(a_base + ks * 32);
#pragma unroll
            for (int t = 0; t < 8; ++t) {
                bf16x8 b = *reinterpret_cast<const bf16x8*>(w_base + (size_t)t * 16 * HD + ks * 32);
                acc[t] = __builtin_amdgcn_mfma_f32_16x16x32_bf16(a, b, acc[t], 0, 0, 0);
            }
        }
        if (s == 1) break;
        a_base = A2 + (size_t)(r0 + lrow) * HD + lkg * 8;
        w_base = W2t + (size_t)lrow * HD + lkg * 8;
    }

#pragma unroll
    for (int t = 0; t < 8; ++t)
#pragma unroll
        for (int r = 0; r < 4; ++r) {
            float v = fmaxf(acc[t][r], 0.f);
            out[(size_t)(r0 + lkg * 4 + r) * HD + t * 16 + lrow] = f2b(v);
        }
}

// ---------------- fused: a2 = softmax(tanh(h@Wc1+bc1) @ Wc2 + bc2) ----------------
// Same GEMM structure; epilogue reduces over cols in-register, never writes t.
__global__ __launch_bounds__(256) void mfma_attn(
    const unsigned short* __restrict__ A1, const unsigned short* __restrict__ W1t,
    const float* __restrict__ bias, const float* __restrict__ Wc2,
    const float* __restrict__ bc2, float* __restrict__ a2, int M)
{
    const int wid = threadIdx.x >> 6;
    const int lane = threadIdx.x & 63;
    const int r0 = (blockIdx.x * 4 + wid) * 16;
    if (r0 >= M) return;
    const int lrow = lane & 15;
    const int lkg = lane >> 4;

    f32x4 acc[8];
#pragma unroll
    for (int t = 0; t < 8; ++t) {
        float b = bias[t * 16 + lrow];
        acc[t] = (f32x4){b, b, b, b};
    }

    const unsigned short* a_base = A1 + (size_t)(r0 + lrow) * HD + lkg * 8;
    const unsigned short* w_base = W1t + (size_t)lrow * HD + lkg * 8;
#pragma unroll
    for (int ks = 0; ks < 4; ++ks) {
        bf16x8 a = *reinterpret_cast<const bf16x8*>(a_base + ks * 32);
#pragma unroll
        for (int t = 0; t < 8; ++t) {
            bf16x8 b = *reinterpret_cast<const bf16x8*>(w_base + (size_t)t * 16 * HD + ks * 32);
            acc[t] = __builtin_amdgcn_mfma_f32_16x16x32_bf16(a, b, acc[t], 0, 0, 0);
        }
    }

    // per-row dot with Wc2 over the 128 cols (cols t*16+lrow, reduce over lrow)
    float p0[4] = {0.f, 0.f, 0.f, 0.f}, p1[4] = {0.f, 0.f, 0.f, 0.f};
#pragma unroll
    for (int t = 0; t < 8; ++t) {
        float2 wv = reinterpret_cast<const float2*>(Wc2)[t * 16 + lrow];
#pragma unroll
        for (int r = 0; r < 4; ++r) {
            float tv = tanhf(acc[t][r]);
            p0[r] = fmaf(tv, wv.x, p0[r]);
            p1[r] = fmaf(tv, wv.y, p1[r]);
        }
    }
#pragma unroll
    for (int off = 1; off < 16; off <<= 1) {
#pragma unroll
        for (int r = 0; r < 4; ++r) {
            p0[r] += __shfl_xor(p0[r], off, 64);
            p1[r] += __shfl_xor(p1[r], off, 64);
        }
    }
    if (lrow == 0) {
        float B0 = bc2[0], B1 = bc2[1];
#pragma unroll
        for (int r = 0; r < 4; ++r) {
            float u0 = p0[r] + B0, u1 = p1[r] + B1;
            float m = fmaxf(u0, u1);
            float e0 = expf(u0 - m), e1 = expf(u1 - m);
            float inv = 1.f / (e0 + e1);
            reinterpret_cast<float2*>(a2)[r0 + lkg * 4 + r] = (float2){e0 * inv, e1 * inv};
        }
    }
}

// ---------------- pos: per-graph sum of a0 * h (8 waves/graph) ----------------
__global__ __launch_bounds__(512) void k_pos(const unsigned short* __restrict__ h,
                                             const float* __restrict__ a2,
                                             const int* __restrict__ batch,
                                             float* __restrict__ pos_out) {
    __shared__ float2 sh[8][64];
    int g = blockIdx.x;
    int lo = 0, hi = NN;
    while (lo < hi) { int m = (lo + hi) >> 1; if (batch[m] < g) lo = m + 1; else hi = m; }
    int beg = lo;
    hi = NN;
    while (lo < hi) { int m = (lo + hi) >> 1; if (batch[m] < g + 1) lo = m + 1; else hi = m; }
    int end = lo;
    int grp = threadIdx.x >> 6;
    int lane = threadIdx.x & 63;
    float2 acc = {0.f, 0.f};
    for (int i = beg + grp; i < end; i += 8) {
        float a = a2[i * 2];
        unsigned int v = *reinterpret_cast<const unsigned int*>(h + (size_t)i * HD + lane * 2);
        acc.x = fmaf(a, b2f(v & 0xffffu), acc.x);
        acc.y = fmaf(a, b2f(v >> 16), acc.y);
    }
    sh[grp][lane] = acc;
    __syncthreads();
    if (threadIdx.x < 64) {
        float2 s = sh[0][lane];
#pragma unroll
        for (int k = 1; k < 8; ++k) { s.x += sh[k][lane].x; s.y += sh[k][lane].y; }
        reinterpret_cast<float2*>(pos_out)[g * 64 + lane] = s;
    }
}

// ---------------- column sums for graph_emb (h bf16, vectorized) ----------------
__global__ __launch_bounds__(256) void k_colsum(const unsigned short* __restrict__ h,
                                                float* __restrict__ csum) {
    __shared__ float2 sh[4][64];
    int lane = threadIdx.x & 63;
    int grp = threadIdx.x >> 6;
    float2 acc = {0.f, 0.f};
    for (int r = blockIdx.x * 4 + grp; r < NN; r += gridDim.x * 4) {
        unsigned int v = *reinterpret_cast<const unsigned int*>(h + (size_t)r * HD + lane * 2);
        acc.x += b2f(v & 0xffffu);
        acc.y += b2f(v >> 16);
    }
    sh[grp][lane] = acc;
    __syncthreads();
    if (threadIdx.x < 64) {
        float2 s = sh[0][lane];
#pragma unroll
        for (int k = 1; k < 4; ++k) { s.x += sh[k][lane].x; s.y += sh[k][lane].y; }
        atomicAdd(&csum[lane * 2], s.x);
        atomicAdd(&csum[lane * 2 + 1], s.y);
    }
}

__global__ void k_gemb(const float* __restrict__ csum, float* __restrict__ out) {
    int i = blockIdx.x * 256 + threadIdx.x;  // 65536
    out[i] = csum[i & 127] * (1.f / (float)NN);
}

// ---------------- new_adj accumulation: LDS-staged atomics ----------------
__global__ __launch_bounds__(256) void k_adj(const int* __restrict__ src, const int* __restrict__ dst,
                                             const int* __restrict__ batch, const float* __restrict__ a2,
                                             float* __restrict__ adj) {
    __shared__ float sh[NG * 4];  // 8 KB
    for (int i = threadIdx.x; i < NG * 4; i += 256) sh[i] = 0.f;
    __syncthreads();
    for (int e = blockIdx.x * 256 + threadIdx.x; e < NE; e += gridDim.x * 256) {
        int s = src[e], d = dst[e];
        int bs = batch[s], bd = batch[d];
        if (bs != bd) continue;
        float a0s = a2[2 * s], a1s = a2[2 * s + 1];
        float a0d = a2[2 * d], a1d = a2[2 * d + 1];
        float* A = sh + bs * 4;
        atomicAdd(A + 0, a0s * a0d);
        atomicAdd(A + 1, a0s * a1d);
        atomicAdd(A + 2, a1s * a0d);
        atomicAdd(A + 3, a1s * a1d);
    }
    __syncthreads();
    for (int i = threadIdx.x; i < NG * 4; i += 256) {
        float v = sh[i];
        if (v != 0.f) atomicAdd(&adj[i], v);
    }
}

__global__ void k_penalty(const float* __restrict__ adj, float* __restrict__ out) {
    __shared__ float sh[512];
    int g = threadIdx.x;  // 512 threads, G=512
    float x0 = adj[g * 4], x1 = adj[g * 4 + 1], x2 = adj[g * 4 + 2], x3 = adj[g * 4 + 3];
    float l0 = fabsf(x0) + fabsf(x1);
    float l1 = fabsf(x2) + fabsf(x3);
    float d0 = x0 / fmaxf(l0, EPSV);
    float d1 = x3 / fmaxf(l1, EPSV);
    sh[g] = 0.5f * ((d0 - 1.f) * (d0 - 1.f) + (d1 - 1.f) * (d1 - 1.f));
    __syncthreads();
    for (int off = 256; off >= 1; off >>= 1) {
        if (g < off) sh[g] += sh[g + off];
        __syncthreads();
    }
    if (g == 0) out[0] = sh[0] * (1.f / (float)NG);
}

// ---------------- fp32 head GEMM (512 rows): out = relu(A@W + b) ----------------
__global__ __launch_bounds__(256) void gemm_head(
    const float* __restrict__ A, const float* __restrict__ W,
    const float* __restrict__ bias, float* __restrict__ out, int M)
{
    const int tid = threadIdx.x;
    const int w = __builtin_amdgcn_readfirstlane(tid >> 6);
    const int lane = tid & 63;
    const int r0 = blockIdx.x * 32 + w * 8;
    if (r0 >= M) return;
    const int c0 = lane, c1 = lane + 64;
    float acc0[8], acc1[8];
    const float b0 = bias[c0], b1 = bias[c1];
#pragma unroll
    for (int r = 0; r < 8; ++r) { acc0[r] = b0; acc1[r] = b1; }
    const float* Ap = A + (size_t)r0 * HD;
    for (int k4 = 0; k4 < HD / 4; ++k4) {
        float4 a[8];
#pragma unroll
        for (int r = 0; r < 8; ++r)
            a[r] = *reinterpret_cast<const float4*>(Ap + r * HD + k4 * 4);
#pragma unroll
        for (int j = 0; j < 4; ++j) {
            const int k = k4 * 4 + j;
            const float w0 = W[k * HD + c0];
            const float w1 = W[k * HD + c1];
#pragma unroll
            for (int r = 0; r < 8; ++r) {
                const float av = (j == 0) ? a[r].x : (j == 1) ? a[r].y
                               : (j == 2) ? a[r].z : a[r].w;
                acc0[r] = fmaf(av, w0, acc0[r]);
                acc1[r] = fmaf(av, w1, acc1[r]);
            }
        }
    }
#pragma unroll
    for (int r = 0; r < 8; ++r) {
        out[(size_t)(r0 + r) * HD + c0] = fmaxf(acc0[r], 0.f);
        out[(size_t)(r0 + r) * HD + c1] = fmaxf(acc1[r], 0.f);
    }
}

// ---------------- final head: logits + log_softmax ----------------
__global__ void k_head(const float* __restrict__ z, const float* __restrict__ Wl2,
                       const float* __restrict__ bl2, float* __restrict__ out0) {
    int g = blockIdx.x * blockDim.x + threadIdx.x;
    if (g >= NG) return;
    float l[NC];
#pragma unroll
    for (int c = 0; c < NC; ++c) l[c] = bl2[c];
    for (int k = 0; k < HD; ++k) {
        float zv = z[(size_t)g * HD + k];
#pragma unroll
        for (int c = 0; c < NC; ++c) l[c] = fmaf(zv, Wl2[k * NC + c], l[c]);
    }
    float m = l[0];
#pragma unroll
    for (int c = 1; c < NC; ++c) m = fmaxf(m, l[c]);
    float sum = 0.f;
#pragma unroll
    for (int c = 0; c < NC; ++c) sum += expf(l[c] - m);
    float lse = m + logf(sum);
#pragma unroll
    for (int c = 0; c < NC; ++c) out0[g * NC + c] = l[c] - lse;
}

extern "C" void kernel_launch(void* const* d_in, const int* in_sizes, int n_in,
                              void* d_out, int out_size, void* d_ws, size_t ws_size,
                              hipStream_t stream) {
    const float* x   = (const float*)d_in[0];
    const int*   ei  = (const int*)d_in[1];
    const int*   src = ei;
    const int*   dst = ei + NE;
    const int*   batch = (const int*)d_in[2];
    const float* W1l = (const float*)d_in[4];
    const float* b1l = (const float*)d_in[5];
    const float* W1r = (const float*)d_in[6];
    const float* W2l = (const float*)d_in[7];
    const float* b2l = (const float*)d_in[8];
    const float* W2r = (const float*)d_in[9];
    const float* Wc1 = (const float*)d_in[10];
    const float* bc1 = (const float*)d_in[11];
    const float* Wc2 = (const float*)d_in[12];
    const float* bc2 = (const float*)d_in[13];
    const float* Wl1 = (const float*)d_in[14];
    const float* bl1 = (const float*)d_in[15];
    const float* Wl2 = (const float*)d_in[16];
    const float* bl2 = (const float*)d_in[17];

    char* ws = (char*)d_ws;
    const size_t BB = (size_t)NN * HD * 2;  // 25,600,000 (bf16 buffer)
    unsigned short* xb   = (unsigned short*)(ws);
    unsigned short* bufA = (unsigned short*)(ws + BB);
    unsigned short* bufB = (unsigned short*)(ws + 2 * BB);
    size_t O = 3 * BB;  // 76,800,000
    int*   cnt     = (int*)(ws + O);
    int*   excl    = (int*)(ws + O + 400000);
    int*   row_off = (int*)(ws + O + 800000);
    int*   fillp   = (int*)(ws + O + 1200064);
    int*   csr     = (int*)(ws + O + 1600064);
    int*   bsum    = (int*)(ws + O + 4160064);
    float* a2      = (float*)(ws + O + 4164160);
    float* adj     = (float*)(ws + O + 4964160);
    float* csum    = (float*)(ws + O + 4972352);
    float* zbuf    = (float*)(ws + O + 4972864);
    unsigned short* w1lt = (unsigned short*)(ws + O + 5235008);
    unsigned short* w1rt = w1lt + 16384;
    unsigned short* w2lt = w1rt + 16384;
    unsigned short* w2rt = w2lt + 16384;
    unsigned short* wc1t = w2rt + 16384;

    float* out0 = (float*)d_out;     // 512*6
    float* pos  = out0 + NG * NC;    // 512*128
    float* gemb = pos + NG * HD;     // 512*128
    float* pen  = gemb + NG * HD;    // 1

    hipMemsetAsync(cnt, 0, NN * 4, stream);
    hipMemsetAsync(fillp, 0, NN * 4, stream);
    hipMemsetAsync(adj, 0, NG * 4 * 4, stream);
    hipMemsetAsync(csum, 0, HD * 4, stream);

    // conversions
    k_cvt<<<6250, 256, 0, stream>>>(x, xb, NN * HD / 8);
    k_prepw<<<64, 256, 0, stream>>>(W1l, w1lt);
    k_prepw<<<64, 256, 0, stream>>>(W1r, w1rt);
    k_prepw<<<64, 256, 0, stream>>>(W2l, w2lt);
    k_prepw<<<64, 256, 0, stream>>>(W2r, w2rt);
    k_prepw<<<64, 256, 0, stream>>>(Wc1, wc1t);

    // CSR build (by dst)
    k_count<<<NE / 256, 256, 0, stream>>>(dst, cnt);
    k_scan1<<<391, 256, 0, stream>>>(cnt, excl, bsum, NN);
    k_scan2<<<1, 512, 0, stream>>>(bsum, 391);
    k_scan3<<<391, 256, 0, stream>>>(excl, bsum, row_off, NN);
    k_fill<<<NE / 256, 256, 0, stream>>>(src, dst, row_off, fillp, csr);

    const int GEMM_GRID = (NN / 16 + 3) / 4;  // 1563
    // Layer 1: h1 = relu(mean@W1l + xb@W1r + b1l) -> bufB
    k_gather_b<<<NN / 4, 256, 0, stream>>>(xb, row_off, csr, bufA);
    mfma_dual<<<GEMM_GRID, 256, 0, stream>>>(bufA, w1lt, xb, w1rt, b1l, bufB, NN);
    // Layer 2: h2 = relu(mean@W2l + h1@W2r + b2l) -> xb
    k_gather_b<<<NN / 4, 256, 0, stream>>>(bufB, row_off, csr, bufA);
    mfma_dual<<<GEMM_GRID, 256, 0, stream>>>(bufA, w2lt, bufB, w2rt, b2l, xb, NN);
    // fused: a = softmax(tanh(h2@Wc1+bc1)@Wc2 + bc2)  (t never materialized)
    mfma_attn<<<GEMM_GRID, 256, 0, stream>>>(xb, wc1t, bc1, Wc2, bc2, a2, NN);
    // pos
    k_pos<<<NG, 512, 0, stream>>>(xb, a2, batch, pos);
    // graph_emb
    k_colsum<<<256, 256, 0, stream>>>(xb, csum);
    k_gemb<<<NG * HD / 256, 256, 0, stream>>>(csum, gemb);
    // new_adj + penalty
    k_adj<<<120, 256, 0, stream>>>(src, dst, batch, a2, adj);
    k_penalty<<<1, 512, 0, stream>>>(adj, pen);
    // head
    gemm_head<<<NG / 32, 256, 0, stream>>>(pos, Wl1, bl1, zbuf, NG);
    k_head<<<2, 256, 0, stream>>>(zbuf, Wl2, bl2, out0);
}

// Round 4
// 419.283 us; speedup vs baseline: 2.2623x; 1.1796x over previous
//
#include <hip/hip_runtime.h>

#define NN 100000
#define NE 640000
#define HD 128
#define NG 512
#define NC 6
#define EPSV 1e-5f

typedef __bf16 bf16_t;
typedef bf16_t bf16x8 __attribute__((ext_vector_type(8)));
typedef float f32x4 __attribute__((ext_vector_type(4)));

__device__ __forceinline__ float b2f(unsigned int u16) {
    return __builtin_bit_cast(float, u16 << 16);
}
__device__ __forceinline__ unsigned short f2b(float f) {
    unsigned int u = __builtin_bit_cast(unsigned int, f);
    unsigned int r = (u + 0x7fffu + ((u >> 16) & 1u)) >> 16;
    return (unsigned short)r;
}

// ---------------- fp32 -> bf16 conversion (x) ----------------
__global__ __launch_bounds__(256) void k_cvt(const float* __restrict__ in,
                                             unsigned short* __restrict__ out, int n8) {
    int i = blockIdx.x * 256 + threadIdx.x;
    if (i >= n8) return;
    float4 v0 = reinterpret_cast<const float4*>(in)[i * 2];
    float4 v1 = reinterpret_cast<const float4*>(in)[i * 2 + 1];
    unsigned short u[8] = {f2b(v0.x), f2b(v0.y), f2b(v0.z), f2b(v0.w),
                           f2b(v1.x), f2b(v1.y), f2b(v1.z), f2b(v1.w)};
    reinterpret_cast<uint4*>(out)[i] = *reinterpret_cast<uint4*>(u);
}

// ---------------- weight transpose + convert: Wt[n][k] = bf16(W[k][n]) ----------------
__global__ __launch_bounds__(256) void k_prepw(const float* __restrict__ W,
                                               unsigned short* __restrict__ Wt) {
    int i = blockIdx.x * 256 + threadIdx.x;  // 16384
    int k = i >> 7, n = i & 127;
    Wt[n * HD + k] = f2b(W[k * HD + n]);
}

// ---------------- counting / CSR build ----------------
__global__ void k_count(const int* __restrict__ dst, int* __restrict__ cnt) {
    int e = blockIdx.x * blockDim.x + threadIdx.x;
    if (e < NE) atomicAdd(&cnt[dst[e]], 1);
}

__global__ void k_scan1(const int* __restrict__ cnt, int* __restrict__ excl,
                        int* __restrict__ bsum, int n) {
    __shared__ int sh[256];
    int i = blockIdx.x * 256 + threadIdx.x;
    int v = (i < n) ? cnt[i] : 0;
    sh[threadIdx.x] = v;
    __syncthreads();
    for (int off = 1; off < 256; off <<= 1) {
        int t = (threadIdx.x >= off) ? sh[threadIdx.x - off] : 0;
        __syncthreads();
        sh[threadIdx.x] += t;
        __syncthreads();
    }
    if (i < n) excl[i] = sh[threadIdx.x] - v;
    if (threadIdx.x == 255) bsum[blockIdx.x] = sh[255];
}

__global__ void k_scan2(int* bsum, int nb) {
    __shared__ int sh[512];
    int t = threadIdx.x;
    sh[t] = (t < nb) ? bsum[t] : 0;
    __syncthreads();
    for (int off = 1; off < 512; off <<= 1) {
        int v = (t >= off) ? sh[t - off] : 0;
        __syncthreads();
        sh[t] += v;
        __syncthreads();
    }
    if (t < nb) bsum[t] = sh[t];
}

__global__ void k_scan3(const int* __restrict__ excl, const int* __restrict__ bsum,
                        int* __restrict__ row_off, int n) {
    int i = blockIdx.x * 256 + threadIdx.x;
    if (i < n) row_off[i] = excl[i] + (blockIdx.x ? bsum[blockIdx.x - 1] : 0);
    if (i == 0) row_off[n] = NE;
}

__global__ void k_fill(const int* __restrict__ src, const int* __restrict__ dst,
                       const int* __restrict__ row_off, int* __restrict__ fillp,
                       int* __restrict__ csr) {
    int e = blockIdx.x * blockDim.x + threadIdx.x;
    if (e < NE) {
        int d = dst[e];
        int p = atomicAdd(&fillp[d], 1);
        csr[row_off[d] + p] = src[e];
    }
}

// ---------------- mean aggregation (gather, 4x unrolled for MLP) ----------------
__global__ __launch_bounds__(256) void k_gather_b(const unsigned short* __restrict__ X,
                                                  const int* __restrict__ row_off,
                                                  const int* __restrict__ csr,
                                                  unsigned short* __restrict__ out) {
    int node = (blockIdx.x * blockDim.x + threadIdx.x) >> 6;
    int lane = threadIdx.x & 63;
    if (node >= NN) return;
    int beg = row_off[node], end = row_off[node + 1];
    float ax0 = 0.f, ay0 = 0.f, ax1 = 0.f, ay1 = 0.f;
    float ax2 = 0.f, ay2 = 0.f, ax3 = 0.f, ay3 = 0.f;
    int j = beg;
    for (; j + 4 <= end; j += 4) {
        int s0 = csr[j], s1 = csr[j + 1], s2 = csr[j + 2], s3 = csr[j + 3];
        unsigned int v0 = *reinterpret_cast<const unsigned int*>(X + (size_t)s0 * HD + lane * 2);
        unsigned int v1 = *reinterpret_cast<const unsigned int*>(X + (size_t)s1 * HD + lane * 2);
        unsigned int v2 = *reinterpret_cast<const unsigned int*>(X + (size_t)s2 * HD + lane * 2);
        unsigned int v3 = *reinterpret_cast<const unsigned int*>(X + (size_t)s3 * HD + lane * 2);
        ax0 += b2f(v0 & 0xffffu); ay0 += b2f(v0 >> 16);
        ax1 += b2f(v1 & 0xffffu); ay1 += b2f(v1 >> 16);
        ax2 += b2f(v2 & 0xffffu); ay2 += b2f(v2 >> 16);
        ax3 += b2f(v3 & 0xffffu); ay3 += b2f(v3 >> 16);
    }
    for (; j < end; ++j) {
        int s = csr[j];
        unsigned int v = *reinterpret_cast<const unsigned int*>(X + (size_t)s * HD + lane * 2);
        ax0 += b2f(v & 0xffffu); ay0 += b2f(v >> 16);
    }
    float ax = (ax0 + ax1) + (ax2 + ax3);
    float ay = (ay0 + ay1) + (ay2 + ay3);
    float inv = 1.f / fmaxf((float)(end - beg), 1.f);
    unsigned int o = (unsigned int)f2b(ax * inv) | ((unsigned int)f2b(ay * inv) << 16);
    *reinterpret_cast<unsigned int*>(out + (size_t)node * HD + lane * 2) = o;
}

// ---------------- MFMA dual-source GEMM: out = relu(A1@W1 + A2@W2 + bias) ----------------
__global__ __launch_bounds__(256) void mfma_dual(
    const unsigned short* __restrict__ A1, const unsigned short* __restrict__ W1t,
    const unsigned short* __restrict__ A2, const unsigned short* __restrict__ W2t,
    const float* __restrict__ bias, unsigned short* __restrict__ out, int M)
{
    const int wid = threadIdx.x >> 6;
    const int lane = threadIdx.x & 63;
    const int r0 = (blockIdx.x * 4 + wid) * 16;
    if (r0 >= M) return;
    const int lrow = lane & 15;
    const int lkg = lane >> 4;

    f32x4 acc[8];
#pragma unroll
    for (int t = 0; t < 8; ++t) {
        float b = bias[t * 16 + lrow];
        acc[t] = (f32x4){b, b, b, b};
    }

    const unsigned short* a_base = A1 + (size_t)(r0 + lrow) * HD + lkg * 8;
    const unsigned short* w_base = W1t + (size_t)lrow * HD + lkg * 8;
    for (int s = 0; s < 2; ++s) {
#pragma unroll
        for (int ks = 0; ks < 4; ++ks) {
            bf16x8 a = *reinterpret_cast<const bf16x8*>(a_base + ks * 32);
#pragma unroll
            for (int t = 0; t < 8; ++t) {
                bf16x8 b = *reinterpret_cast<const bf16x8*>(w_base + (size_t)t * 16 * HD + ks * 32);
                acc[t] = __builtin_amdgcn_mfma_f32_16x16x32_bf16(a, b, acc[t], 0, 0, 0);
            }
        }
        if (s == 1) break;
        a_base = A2 + (size_t)(r0 + lrow) * HD + lkg * 8;
        w_base = W2t + (size_t)lrow * HD + lkg * 8;
    }

#pragma unroll
    for (int t = 0; t < 8; ++t)
#pragma unroll
        for (int r = 0; r < 4; ++r) {
            float v = fmaxf(acc[t][r], 0.f);
            out[(size_t)(r0 + lkg * 4 + r) * HD + t * 16 + lrow] = f2b(v);
        }
}

// ---------------- fused: a2 = softmax(tanh(h@Wc1+bc1) @ Wc2 + bc2) ----------------
__global__ __launch_bounds__(256) void mfma_attn(
    const unsigned short* __restrict__ A1, const unsigned short* __restrict__ W1t,
    const float* __restrict__ bias, const float* __restrict__ Wc2,
    const float* __restrict__ bc2, float* __restrict__ a2, int M)
{
    const int wid = threadIdx.x >> 6;
    const int lane = threadIdx.x & 63;
    const int r0 = (blockIdx.x * 4 + wid) * 16;
    if (r0 >= M) return;
    const int lrow = lane & 15;
    const int lkg = lane >> 4;

    f32x4 acc[8];
#pragma unroll
    for (int t = 0; t < 8; ++t) {
        float b = bias[t * 16 + lrow];
        acc[t] = (f32x4){b, b, b, b};
    }

    const unsigned short* a_base = A1 + (size_t)(r0 + lrow) * HD + lkg * 8;
    const unsigned short* w_base = W1t + (size_t)lrow * HD + lkg * 8;
#pragma unroll
    for (int ks = 0; ks < 4; ++ks) {
        bf16x8 a = *reinterpret_cast<const bf16x8*>(a_base + ks * 32);
#pragma unroll
        for (int t = 0; t < 8; ++t) {
            bf16x8 b = *reinterpret_cast<const bf16x8*>(w_base + (size_t)t * 16 * HD + ks * 32);
            acc[t] = __builtin_amdgcn_mfma_f32_16x16x32_bf16(a, b, acc[t], 0, 0, 0);
        }
    }

    float p0[4] = {0.f, 0.f, 0.f, 0.f}, p1[4] = {0.f, 0.f, 0.f, 0.f};
#pragma unroll
    for (int t = 0; t < 8; ++t) {
        float2 wv = reinterpret_cast<const float2*>(Wc2)[t * 16 + lrow];
#pragma unroll
        for (int r = 0; r < 4; ++r) {
            float tv = tanhf(acc[t][r]);
            p0[r] = fmaf(tv, wv.x, p0[r]);
            p1[r] = fmaf(tv, wv.y, p1[r]);
        }
    }
#pragma unroll
    for (int off = 1; off < 16; off <<= 1) {
#pragma unroll
        for (int r = 0; r < 4; ++r) {
            p0[r] += __shfl_xor(p0[r], off, 64);
            p1[r] += __shfl_xor(p1[r], off, 64);
        }
    }
    if (lrow == 0) {
        float B0 = bc2[0], B1 = bc2[1];
#pragma unroll
        for (int r = 0; r < 4; ++r) {
            float u0 = p0[r] + B0, u1 = p1[r] + B1;
            float m = fmaxf(u0, u1);
            float e0 = expf(u0 - m), e1 = expf(u1 - m);
            float inv = 1.f / (e0 + e1);
            reinterpret_cast<float2*>(a2)[r0 + lkg * 4 + r] = (float2){e0 * inv, e1 * inv};
        }
    }
}

// ---------------- pos + colsum fused: per-graph a0-weighted sum AND plain sum ----------------
__global__ __launch_bounds__(512) void k_pos(const unsigned short* __restrict__ h,
                                             const float* __restrict__ a2,
                                             const int* __restrict__ batch,
                                             float* __restrict__ pos_out,
                                             float* __restrict__ csum) {
    __shared__ float4 sh[8][64];
    int g = blockIdx.x;
    int lo = 0, hi = NN;
    while (lo < hi) { int m = (lo + hi) >> 1; if (batch[m] < g) lo = m + 1; else hi = m; }
    int beg = lo;
    hi = NN;
    while (lo < hi) { int m = (lo + hi) >> 1; if (batch[m] < g + 1) lo = m + 1; else hi = m; }
    int end = lo;
    int grp = threadIdx.x >> 6;
    int lane = threadIdx.x & 63;
    float4 acc = {0.f, 0.f, 0.f, 0.f};  // xy = weighted, zw = plain
    for (int i = beg + grp; i < end; i += 8) {
        float a = a2[i * 2];
        unsigned int v = *reinterpret_cast<const unsigned int*>(h + (size_t)i * HD + lane * 2);
        float f0 = b2f(v & 0xffffu), f1 = b2f(v >> 16);
        acc.x = fmaf(a, f0, acc.x);
        acc.y = fmaf(a, f1, acc.y);
        acc.z += f0;
        acc.w += f1;
    }
    sh[grp][lane] = acc;
    __syncthreads();
    if (threadIdx.x < 64) {
        float4 s = sh[0][lane];
#pragma unroll
        for (int k = 1; k < 8; ++k) {
            float4 t = sh[k][lane];
            s.x += t.x; s.y += t.y; s.z += t.z; s.w += t.w;
        }
        reinterpret_cast<float2*>(pos_out)[g * 64 + lane] = (float2){s.x, s.y};
        atomicAdd(&csum[lane * 2], s.z);
        atomicAdd(&csum[lane * 2 + 1], s.w);
    }
}

__global__ void k_gemb(const float* __restrict__ csum, float* __restrict__ out) {
    int i = blockIdx.x * 256 + threadIdx.x;  // 65536
    out[i] = csum[i & 127] * (1.f / (float)NN);
}

// ---------------- new_adj accumulation: LDS-staged atomics ----------------
__global__ __launch_bounds__(256) void k_adj(const int* __restrict__ src, const int* __restrict__ dst,
                                             const int* __restrict__ batch, const float* __restrict__ a2,
                                             float* __restrict__ adj) {
    __shared__ float sh[NG * 4];  // 8 KB
    for (int i = threadIdx.x; i < NG * 4; i += 256) sh[i] = 0.f;
    __syncthreads();
    for (int e = blockIdx.x * 256 + threadIdx.x; e < NE; e += gridDim.x * 256) {
        int s = src[e], d = dst[e];
        int bs = batch[s], bd = batch[d];
        if (bs != bd) continue;
        float a0s = a2[2 * s], a1s = a2[2 * s + 1];
        float a0d = a2[2 * d], a1d = a2[2 * d + 1];
        float* A = sh + bs * 4;
        atomicAdd(A + 0, a0s * a0d);
        atomicAdd(A + 1, a0s * a1d);
        atomicAdd(A + 2, a1s * a0d);
        atomicAdd(A + 3, a1s * a1d);
    }
    __syncthreads();
    for (int i = threadIdx.x; i < NG * 4; i += 256) {
        float v = sh[i];
        if (v != 0.f) atomicAdd(&adj[i], v);
    }
}

__global__ void k_penalty(const float* __restrict__ adj, float* __restrict__ out) {
    __shared__ float sh[512];
    int g = threadIdx.x;  // 512 threads, G=512
    float x0 = adj[g * 4], x1 = adj[g * 4 + 1], x2 = adj[g * 4 + 2], x3 = adj[g * 4 + 3];
    float l0 = fabsf(x0) + fabsf(x1);
    float l1 = fabsf(x2) + fabsf(x3);
    float d0 = x0 / fmaxf(l0, EPSV);
    float d1 = x3 / fmaxf(l1, EPSV);
    sh[g] = 0.5f * ((d0 - 1.f) * (d0 - 1.f) + (d1 - 1.f) * (d1 - 1.f));
    __syncthreads();
    for (int off = 256; off >= 1; off >>= 1) {
        if (g < off) sh[g] += sh[g + off];
        __syncthreads();
    }
    if (g == 0) out[0] = sh[0] * (1.f / (float)NG);
}

// ---------------- fp32 head GEMM (512 rows): out = relu(A@W + b) ----------------
__global__ __launch_bounds__(256) void gemm_head(
    const float* __restrict__ A, const float* __restrict__ W,
    const float* __restrict__ bias, float* __restrict__ out, int M)
{
    const int tid = threadIdx.x;
    const int w = __builtin_amdgcn_readfirstlane(tid >> 6);
    const int lane = tid & 63;
    const int r0 = blockIdx.x * 32 + w * 8;
    if (r0 >= M) return;
    const int c0 = lane, c1 = lane + 64;
    float acc0[8], acc1[8];
    const float b0 = bias[c0], b1 = bias[c1];
#pragma unroll
    for (int r = 0; r < 8; ++r) { acc0[r] = b0; acc1[r] = b1; }
    const float* Ap = A + (size_t)r0 * HD;
    for (int k4 = 0; k4 < HD / 4; ++k4) {
        float4 a[8];
#pragma unroll
        for (int r = 0; r < 8; ++r)
            a[r] = *reinterpret_cast<const float4*>(Ap + r * HD + k4 * 4);
#pragma unroll
        for (int j = 0; j < 4; ++j) {
            const int k = k4 * 4 + j;
            const float w0 = W[k * HD + c0];
            const float w1 = W[k * HD + c1];
#pragma unroll
            for (int r = 0; r < 8; ++r) {
                const float av = (j == 0) ? a[r].x : (j == 1) ? a[r].y
                               : (j == 2) ? a[r].z : a[r].w;
                acc0[r] = fmaf(av, w0, acc0[r]);
                acc1[r] = fmaf(av, w1, acc1[r]);
            }
        }
    }
#pragma unroll
    for (int r = 0; r < 8; ++r) {
        out[(size_t)(r0 + r) * HD + c0] = fmaxf(acc0[r], 0.f);
        out[(size_t)(r0 + r) * HD + c1] = fmaxf(acc1[r], 0.f);
    }
}

// ---------------- final head: logits + log_softmax ----------------
__global__ void k_head(const float* __restrict__ z, const float* __restrict__ Wl2,
                       const float* __restrict__ bl2, float* __restrict__ out0) {
    int g = blockIdx.x * blockDim.x + threadIdx.x;
    if (g >= NG) return;
    float l[NC];
#pragma unroll
    for (int c = 0; c < NC; ++c) l[c] = bl2[c];
    for (int k = 0; k < HD; ++k) {
        float zv = z[(size_t)g * HD + k];
#pragma unroll
        for (int c = 0; c < NC; ++c) l[c] = fmaf(zv, Wl2[k * NC + c], l[c]);
    }
    float m = l[0];
#pragma unroll
    for (int c = 1; c < NC; ++c) m = fmaxf(m, l[c]);
    float sum = 0.f;
#pragma unroll
    for (int c = 0; c < NC; ++c) sum += expf(l[c] - m);
    float lse = m + logf(sum);
#pragma unroll
    for (int c = 0; c < NC; ++c) out0[g * NC + c] = l[c] - lse;
}

extern "C" void kernel_launch(void* const* d_in, const int* in_sizes, int n_in,
                              void* d_out, int out_size, void* d_ws, size_t ws_size,
                              hipStream_t stream) {
    const float* x   = (const float*)d_in[0];
    const int*   ei  = (const int*)d_in[1];
    const int*   src = ei;
    const int*   dst = ei + NE;
    const int*   batch = (const int*)d_in[2];
    const float* W1l = (const float*)d_in[4];
    const float* b1l = (const float*)d_in[5];
    const float* W1r = (const float*)d_in[6];
    const float* W2l = (const float*)d_in[7];
    const float* b2l = (const float*)d_in[8];
    const float* W2r = (const float*)d_in[9];
    const float* Wc1 = (const float*)d_in[10];
    const float* bc1 = (const float*)d_in[11];
    const float* Wc2 = (const float*)d_in[12];
    const float* bc2 = (const float*)d_in[13];
    const float* Wl1 = (const float*)d_in[14];
    const float* bl1 = (const float*)d_in[15];
    const float* Wl2 = (const float*)d_in[16];
    const float* bl2 = (const float*)d_in[17];

    char* ws = (char*)d_ws;
    const size_t BB = (size_t)NN * HD * 2;  // 25,600,000 (bf16 buffer)
    unsigned short* xb   = (unsigned short*)(ws);
    unsigned short* bufA = (unsigned short*)(ws + BB);
    unsigned short* bufB = (unsigned short*)(ws + 2 * BB);
    size_t O = 3 * BB;  // 76,800,000
    int*   cnt     = (int*)(ws + O);
    int*   excl    = (int*)(ws + O + 400000);
    int*   row_off = (int*)(ws + O + 800000);
    int*   fillp   = (int*)(ws + O + 1200064);
    int*   csr     = (int*)(ws + O + 1600064);
    int*   bsum    = (int*)(ws + O + 4160064);
    float* a2      = (float*)(ws + O + 4164160);
    float* adj     = (float*)(ws + O + 4964160);
    float* csum    = (float*)(ws + O + 4972352);
    float* zbuf    = (float*)(ws + O + 4972864);
    unsigned short* w1lt = (unsigned short*)(ws + O + 5235008);
    unsigned short* w1rt = w1lt + 16384;
    unsigned short* w2lt = w1rt + 16384;
    unsigned short* w2rt = w2lt + 16384;
    unsigned short* wc1t = w2rt + 16384;

    float* out0 = (float*)d_out;     // 512*6
    float* pos  = out0 + NG * NC;    // 512*128
    float* gemb = pos + NG * HD;     // 512*128
    float* pen  = gemb + NG * HD;    // 1

    hipMemsetAsync(cnt, 0, NN * 4, stream);
    hipMemsetAsync(fillp, 0, NN * 4, stream);
    hipMemsetAsync(adj, 0, NG * 4 * 4, stream);
    hipMemsetAsync(csum, 0, HD * 4, stream);

    // conversions
    k_cvt<<<6250, 256, 0, stream>>>(x, xb, NN * HD / 8);
    k_prepw<<<64, 256, 0, stream>>>(W1l, w1lt);
    k_prepw<<<64, 256, 0, stream>>>(W1r, w1rt);
    k_prepw<<<64, 256, 0, stream>>>(W2l, w2lt);
    k_prepw<<<64, 256, 0, stream>>>(W2r, w2rt);
    k_prepw<<<64, 256, 0, stream>>>(Wc1, wc1t);

    // CSR build (by dst)
    k_count<<<NE / 256, 256, 0, stream>>>(dst, cnt);
    k_scan1<<<391, 256, 0, stream>>>(cnt, excl, bsum, NN);
    k_scan2<<<1, 512, 0, stream>>>(bsum, 391);
    k_scan3<<<391, 256, 0, stream>>>(excl, bsum, row_off, NN);
    k_fill<<<NE / 256, 256, 0, stream>>>(src, dst, row_off, fillp, csr);

    const int GEMM_GRID = (NN / 16 + 3) / 4;  // 1563
    // Layer 1: h1 = relu(mean@W1l + xb@W1r + b1l) -> bufB
    k_gather_b<<<NN / 4, 256, 0, stream>>>(xb, row_off, csr, bufA);
    mfma_dual<<<GEMM_GRID, 256, 0, stream>>>(bufA, w1lt, xb, w1rt, b1l, bufB, NN);
    // Layer 2: h2 = relu(mean@W2l + h1@W2r + b2l) -> xb
    k_gather_b<<<NN / 4, 256, 0, stream>>>(bufB, row_off, csr, bufA);
    mfma_dual<<<GEMM_GRID, 256, 0, stream>>>(bufA, w2lt, bufB, w2rt, b2l, xb, NN);
    // fused: a = softmax(tanh(h2@Wc1+bc1)@Wc2 + bc2)
    mfma_attn<<<GEMM_GRID, 256, 0, stream>>>(xb, wc1t, bc1, Wc2, bc2, a2, NN);
    // pos + colsum fused
    k_pos<<<NG, 512, 0, stream>>>(xb, a2, batch, pos, csum);
    // graph_emb
    k_gemb<<<NG * HD / 256, 256, 0, stream>>>(csum, gemb);
    // new_adj + penalty
    k_adj<<<120, 256, 0, stream>>>(src, dst, batch, a2, adj);
    k_penalty<<<1, 512, 0, stream>>>(adj, pen);
    // head
    gemm_head<<<NG / 32, 256, 0, stream>>>(pos, Wl1, bl1, zbuf, NG);
    k_head<<<2, 256, 0, stream>>>(zbuf, Wl2, bl2, out0);
}

// Round 5
// 336.559 us; speedup vs baseline: 2.8183x; 1.2458x over previous
//
#include <hip/hip_runtime.h>

#define NN 100000
#define NE 640000
#define HD 128
#define NG 512
#define NC 6
#define EPSV 1e-5f

typedef __bf16 bf16_t;
typedef bf16_t bf16x8 __attribute__((ext_vector_type(8)));
typedef float f32x4 __attribute__((ext_vector_type(4)));
typedef unsigned short ushort_t;

__device__ __forceinline__ float b2f(unsigned int u16) {
    return __builtin_bit_cast(float, u16 << 16);
}
__device__ __forceinline__ unsigned short f2b(float f) {
    unsigned int u = __builtin_bit_cast(unsigned int, f);
    unsigned int r = (u + 0x7fffu + ((u >> 16) & 1u)) >> 16;
    return (unsigned short)r;
}

// ---------------- fp32 -> bf16 conversion (x) ----------------
__global__ __launch_bounds__(256) void k_cvt(const float* __restrict__ in,
                                             unsigned short* __restrict__ out, int n8) {
    int i = blockIdx.x * 256 + threadIdx.x;
    if (i >= n8) return;
    float4 v0 = reinterpret_cast<const float4*>(in)[i * 2];
    float4 v1 = reinterpret_cast<const float4*>(in)[i * 2 + 1];
    unsigned short u[8] = {f2b(v0.x), f2b(v0.y), f2b(v0.z), f2b(v0.w),
                           f2b(v1.x), f2b(v1.y), f2b(v1.z), f2b(v1.w)};
    reinterpret_cast<uint4*>(out)[i] = *reinterpret_cast<uint4*>(u);
}

// ---------------- weight transpose + convert: Wt[n][k] = bf16(W[k][n]) ----------------
__global__ __launch_bounds__(256) void k_prepw(const float* __restrict__ W,
                                               unsigned short* __restrict__ Wt) {
    int i = blockIdx.x * 256 + threadIdx.x;  // 16384
    int k = i >> 7, n = i & 127;
    Wt[n * HD + k] = f2b(W[k * HD + n]);
}

// ---------------- counting / CSR build ----------------
__global__ void k_count(const int* __restrict__ dst, int* __restrict__ cnt) {
    int e = blockIdx.x * blockDim.x + threadIdx.x;
    if (e < NE) atomicAdd(&cnt[dst[e]], 1);
}

__global__ void k_scan1(const int* __restrict__ cnt, int* __restrict__ excl,
                        int* __restrict__ bsum, int n) {
    __shared__ int sh[256];
    int i = blockIdx.x * 256 + threadIdx.x;
    int v = (i < n) ? cnt[i] : 0;
    sh[threadIdx.x] = v;
    __syncthreads();
    for (int off = 1; off < 256; off <<= 1) {
        int t = (threadIdx.x >= off) ? sh[threadIdx.x - off] : 0;
        __syncthreads();
        sh[threadIdx.x] += t;
        __syncthreads();
    }
    if (i < n) excl[i] = sh[threadIdx.x] - v;
    if (threadIdx.x == 255) bsum[blockIdx.x] = sh[255];
}

__global__ void k_scan2(int* bsum, int nb) {
    __shared__ int sh[512];
    int t = threadIdx.x;
    sh[t] = (t < nb) ? bsum[t] : 0;
    __syncthreads();
    for (int off = 1; off < 512; off <<= 1) {
        int v = (t >= off) ? sh[t - off] : 0;
        __syncthreads();
        sh[t] += v;
        __syncthreads();
    }
    if (t < nb) bsum[t] = sh[t];
}

__global__ void k_scan3(const int* __restrict__ excl, const int* __restrict__ bsum,
                        int* __restrict__ row_off, int n) {
    int i = blockIdx.x * 256 + threadIdx.x;
    if (i < n) row_off[i] = excl[i] + (blockIdx.x ? bsum[blockIdx.x - 1] : 0);
    if (i == 0) row_off[n] = NE;
}

__global__ void k_fill(const int* __restrict__ src, const int* __restrict__ dst,
                       const int* __restrict__ row_off, int* __restrict__ fillp,
                       int* __restrict__ csr) {
    int e = blockIdx.x * blockDim.x + threadIdx.x;
    if (e < NE) {
        int d = dst[e];
        int p = atomicAdd(&fillp[d], 1);
        csr[row_off[d] + p] = src[e];
    }
}

// ---------------- mean aggregation: 4 neighbors/step, 16B loads/lane ----------------
// lane = grp(neighbor 0..3) x sub(col-chunk 0..15); cross-group shfl reduce.
__global__ __launch_bounds__(256) void k_gather_b(const unsigned short* __restrict__ X,
                                                  const int* __restrict__ row_off,
                                                  const int* __restrict__ csr,
                                                  unsigned short* __restrict__ out) {
    int node = (blockIdx.x * blockDim.x + threadIdx.x) >> 6;
    int lane = threadIdx.x & 63;
    if (node >= NN) return;
    int beg = row_off[node], end = row_off[node + 1];
    int grp = lane >> 4;
    int sub = lane & 15;
    float acc[8] = {0.f, 0.f, 0.f, 0.f, 0.f, 0.f, 0.f, 0.f};
    for (int j = beg; j < end; j += 4) {
        int jj = j + grp;
        bool valid = jj < end;
        int s = csr[valid ? jj : beg];
        uint4 v = *reinterpret_cast<const uint4*>(X + (size_t)s * HD + sub * 8);
        if (valid) {
            acc[0] += b2f(v.x & 0xffffu); acc[1] += b2f(v.x >> 16);
            acc[2] += b2f(v.y & 0xffffu); acc[3] += b2f(v.y >> 16);
            acc[4] += b2f(v.z & 0xffffu); acc[5] += b2f(v.z >> 16);
            acc[6] += b2f(v.w & 0xffffu); acc[7] += b2f(v.w >> 16);
        }
    }
#pragma unroll
    for (int k = 0; k < 8; ++k) {
        acc[k] += __shfl_xor(acc[k], 16, 64);
        acc[k] += __shfl_xor(acc[k], 32, 64);
    }
    if (grp == 0) {
        float inv = 1.f / fmaxf((float)(end - beg), 1.f);
        unsigned short u[8];
#pragma unroll
        for (int k = 0; k < 8; ++k) u[k] = f2b(acc[k] * inv);
        *reinterpret_cast<uint4*>(out + (size_t)node * HD + sub * 8) = *reinterpret_cast<uint4*>(u);
    }
}

// ---------------- MFMA dual-source GEMM, LDS-staged weights, 2-phase ----------------
// 4 waves x 32 rows = 128 rows/block. W staged in 32KB LDS with XOR swizzle.
__global__ __launch_bounds__(256) void mfma_dual(
    const unsigned short* __restrict__ A1, const unsigned short* __restrict__ W1t,
    const unsigned short* __restrict__ A2, const unsigned short* __restrict__ W2t,
    const float* __restrict__ bias, unsigned short* __restrict__ out, int M)
{
    __shared__ uint4 wlds[2048];  // 32 KB
    const int wid = threadIdx.x >> 6;
    const int lane = threadIdx.x & 63;
    const int lrow = lane & 15;
    const int lkg = lane >> 4;
    const int r0 = blockIdx.x * 128 + wid * 32;

    // all A-frag loads issued up front (both sources, both 16-row groups)
    bf16x8 a[2][2][4];
#pragma unroll
    for (int s = 0; s < 2; ++s) {
        const unsigned short* Ap = s ? A2 : A1;
#pragma unroll
        for (int g = 0; g < 2; ++g) {
            int row = r0 + g * 16 + lrow;
            row = row < M ? row : M - 1;
            const unsigned short* p = Ap + (size_t)row * HD + lkg * 8;
#pragma unroll
            for (int ks = 0; ks < 4; ++ks)
                a[s][g][ks] = *reinterpret_cast<const bf16x8*>(p + ks * 32);
        }
    }

    f32x4 acc[2][8];
#pragma unroll
    for (int t = 0; t < 8; ++t) {
        float b = bias[t * 16 + lrow];
        acc[0][t] = (f32x4){b, b, b, b};
        acc[1][t] = (f32x4){b, b, b, b};
    }

    const char* ldsb = (const char*)wlds;
#pragma unroll
    for (int s = 0; s < 2; ++s) {
        const uint4* g4 = reinterpret_cast<const uint4*>(s ? W2t : W1t);
        if (s) __syncthreads();  // phase-1 LDS reads complete before restage
        for (int i = threadIdx.x; i < 2048; i += 256) {
            int di = i ^ ((i >> 4) & 7);  // granule swizzle (row&7)
            wlds[di] = g4[i];
        }
        __syncthreads();
#pragma unroll
        for (int ks = 0; ks < 4; ++ks) {
#pragma unroll
            for (int t = 0; t < 8; ++t) {
                int off = (lrow * 256 + lkg * 16 + t * 4096 + ks * 64) ^ ((lrow & 7) << 4);
                bf16x8 b = *reinterpret_cast<const bf16x8*>(ldsb + off);
                acc[0][t] = __builtin_amdgcn_mfma_f32_16x16x32_bf16(a[s][0][ks], b, acc[0][t], 0, 0, 0);
                acc[1][t] = __builtin_amdgcn_mfma_f32_16x16x32_bf16(a[s][1][ks], b, acc[1][t], 0, 0, 0);
            }
        }
    }

#pragma unroll
    for (int g = 0; g < 2; ++g)
#pragma unroll
        for (int t = 0; t < 8; ++t)
#pragma unroll
            for (int r = 0; r < 4; ++r) {
                int row = r0 + g * 16 + lkg * 4 + r;
                if (row < M) {
                    float v = fmaxf(acc[g][t][r], 0.f);
                    out[(size_t)row * HD + t * 16 + lrow] = f2b(v);
                }
            }
}

// ---------------- fused: a2 = softmax(tanh(h@Wc1+bc1) @ Wc2 + bc2), LDS weights ----------------
__global__ __launch_bounds__(256) void mfma_attn(
    const unsigned short* __restrict__ A1, const unsigned short* __restrict__ W1t,
    const float* __restrict__ bias, const float* __restrict__ Wc2,
    const float* __restrict__ bc2, float* __restrict__ a2, int M)
{
    __shared__ uint4 wlds[2048];
    const int wid = threadIdx.x >> 6;
    const int lane = threadIdx.x & 63;
    const int lrow = lane & 15;
    const int lkg = lane >> 4;
    const int r0 = blockIdx.x * 128 + wid * 32;

    bf16x8 a[2][4];
#pragma unroll
    for (int g = 0; g < 2; ++g) {
        int row = r0 + g * 16 + lrow;
        row = row < M ? row : M - 1;
        const unsigned short* p = A1 + (size_t)row * HD + lkg * 8;
#pragma unroll
        for (int ks = 0; ks < 4; ++ks)
            a[g][ks] = *reinterpret_cast<const bf16x8*>(p + ks * 32);
    }

    f32x4 acc[2][8];
#pragma unroll
    for (int t = 0; t < 8; ++t) {
        float b = bias[t * 16 + lrow];
        acc[0][t] = (f32x4){b, b, b, b};
        acc[1][t] = (f32x4){b, b, b, b};
    }

    const uint4* g4 = reinterpret_cast<const uint4*>(W1t);
    for (int i = threadIdx.x; i < 2048; i += 256) {
        int di = i ^ ((i >> 4) & 7);
        wlds[di] = g4[i];
    }
    __syncthreads();

    const char* ldsb = (const char*)wlds;
#pragma unroll
    for (int ks = 0; ks < 4; ++ks) {
#pragma unroll
        for (int t = 0; t < 8; ++t) {
            int off = (lrow * 256 + lkg * 16 + t * 4096 + ks * 64) ^ ((lrow & 7) << 4);
            bf16x8 b = *reinterpret_cast<const bf16x8*>(ldsb + off);
            acc[0][t] = __builtin_amdgcn_mfma_f32_16x16x32_bf16(a[0][ks], b, acc[0][t], 0, 0, 0);
            acc[1][t] = __builtin_amdgcn_mfma_f32_16x16x32_bf16(a[1][ks], b, acc[1][t], 0, 0, 0);
        }
    }

    float p0[2][4] = {{0.f, 0.f, 0.f, 0.f}, {0.f, 0.f, 0.f, 0.f}};
    float p1[2][4] = {{0.f, 0.f, 0.f, 0.f}, {0.f, 0.f, 0.f, 0.f}};
#pragma unroll
    for (int t = 0; t < 8; ++t) {
        float2 wv = reinterpret_cast<const float2*>(Wc2)[t * 16 + lrow];
#pragma unroll
        for (int g = 0; g < 2; ++g)
#pragma unroll
            for (int r = 0; r < 4; ++r) {
                float tv = tanhf(acc[g][t][r]);
                p0[g][r] = fmaf(tv, wv.x, p0[g][r]);
                p1[g][r] = fmaf(tv, wv.y, p1[g][r]);
            }
    }
#pragma unroll
    for (int off = 1; off < 16; off <<= 1) {
#pragma unroll
        for (int g = 0; g < 2; ++g)
#pragma unroll
            for (int r = 0; r < 4; ++r) {
                p0[g][r] += __shfl_xor(p0[g][r], off, 64);
                p1[g][r] += __shfl_xor(p1[g][r], off, 64);
            }
    }
    if (lrow == 0) {
        float B0 = bc2[0], B1 = bc2[1];
#pragma unroll
        for (int g = 0; g < 2; ++g)
#pragma unroll
            for (int r = 0; r < 4; ++r) {
                int row = r0 + g * 16 + lkg * 4 + r;
                if (row < M) {
                    float u0 = p0[g][r] + B0, u1 = p1[g][r] + B1;
                    float m = fmaxf(u0, u1);
                    float e0 = expf(u0 - m), e1 = expf(u1 - m);
                    float inv = 1.f / (e0 + e1);
                    reinterpret_cast<float2*>(a2)[row] = (float2){e0 * inv, e1 * inv};
                }
            }
    }
}

// ---------------- pos + colsum fused ----------------
__global__ __launch_bounds__(512) void k_pos(const unsigned short* __restrict__ h,
                                             const float* __restrict__ a2,
                                             const int* __restrict__ batch,
                                             float* __restrict__ pos_out,
                                             float* __restrict__ csum) {
    __shared__ float4 sh[8][64];
    int g = blockIdx.x;
    int lo = 0, hi = NN;
    while (lo < hi) { int m = (lo + hi) >> 1; if (batch[m] < g) lo = m + 1; else hi = m; }
    int beg = lo;
    hi = NN;
    while (lo < hi) { int m = (lo + hi) >> 1; if (batch[m] < g + 1) lo = m + 1; else hi = m; }
    int end = lo;
    int grp = threadIdx.x >> 6;
    int lane = threadIdx.x & 63;
    float4 acc = {0.f, 0.f, 0.f, 0.f};
    for (int i = beg + grp; i < end; i += 8) {
        float a = a2[i * 2];
        unsigned int v = *reinterpret_cast<const unsigned int*>(h + (size_t)i * HD + lane * 2);
        float f0 = b2f(v & 0xffffu), f1 = b2f(v >> 16);
        acc.x = fmaf(a, f0, acc.x);
        acc.y = fmaf(a, f1, acc.y);
        acc.z += f0;
        acc.w += f1;
    }
    sh[grp][lane] = acc;
    __syncthreads();
    if (threadIdx.x < 64) {
        float4 s = sh[0][lane];
#pragma unroll
        for (int k = 1; k < 8; ++k) {
            float4 t = sh[k][lane];
            s.x += t.x; s.y += t.y; s.z += t.z; s.w += t.w;
        }
        reinterpret_cast<float2*>(pos_out)[g * 64 + lane] = (float2){s.x, s.y};
        atomicAdd(&csum[lane * 2], s.z);
        atomicAdd(&csum[lane * 2 + 1], s.w);
    }
}

__global__ void k_gemb(const float* __restrict__ csum, float* __restrict__ out) {
    int i = blockIdx.x * 256 + threadIdx.x;  // 65536
    out[i] = csum[i & 127] * (1.f / (float)NN);
}

// ---------------- new_adj accumulation: LDS-staged atomics ----------------
__global__ __launch_bounds__(256) void k_adj(const int* __restrict__ src, const int* __restrict__ dst,
                                             const int* __restrict__ batch, const float* __restrict__ a2,
                                             float* __restrict__ adj) {
    __shared__ float sh[NG * 4];  // 8 KB
    for (int i = threadIdx.x; i < NG * 4; i += 256) sh[i] = 0.f;
    __syncthreads();
    for (int e = blockIdx.x * 256 + threadIdx.x; e < NE; e += gridDim.x * 256) {
        int s = src[e], d = dst[e];
        int bs = batch[s], bd = batch[d];
        if (bs != bd) continue;
        float a0s = a2[2 * s], a1s = a2[2 * s + 1];
        float a0d = a2[2 * d], a1d = a2[2 * d + 1];
        float* A = sh + bs * 4;
        atomicAdd(A + 0, a0s * a0d);
        atomicAdd(A + 1, a0s * a1d);
        atomicAdd(A + 2, a1s * a0d);
        atomicAdd(A + 3, a1s * a1d);
    }
    __syncthreads();
    for (int i = threadIdx.x; i < NG * 4; i += 256) {
        float v = sh[i];
        if (v != 0.f) atomicAdd(&adj[i], v);
    }
}

__global__ void k_penalty(const float* __restrict__ adj, float* __restrict__ out) {
    __shared__ float sh[512];
    int g = threadIdx.x;
    float x0 = adj[g * 4], x1 = adj[g * 4 + 1], x2 = adj[g * 4 + 2], x3 = adj[g * 4 + 3];
    float l0 = fabsf(x0) + fabsf(x1);
    float l1 = fabsf(x2) + fabsf(x3);
    float d0 = x0 / fmaxf(l0, EPSV);
    float d1 = x3 / fmaxf(l1, EPSV);
    sh[g] = 0.5f * ((d0 - 1.f) * (d0 - 1.f) + (d1 - 1.f) * (d1 - 1.f));
    __syncthreads();
    for (int off = 256; off >= 1; off >>= 1) {
        if (g < off) sh[g] += sh[g + off];
        __syncthreads();
    }
    if (g == 0) out[0] = sh[0] * (1.f / (float)NG);
}

// ---------------- fp32 head GEMM (512 rows): out = relu(A@W + b) ----------------
__global__ __launch_bounds__(256) void gemm_head(
    const float* __restrict__ A, const float* __restrict__ W,
    const float* __restrict__ bias, float* __restrict__ out, int M)
{
    const int tid = threadIdx.x;
    const int w = __builtin_amdgcn_readfirstlane(tid >> 6);
    const int lane = tid & 63;
    const int r0 = blockIdx.x * 32 + w * 8;
    if (r0 >= M) return;
    const int c0 = lane, c1 = lane + 64;
    float acc0[8], acc1[8];
    const float b0 = bias[c0], b1 = bias[c1];
#pragma unroll
    for (int r = 0; r < 8; ++r) { acc0[r] = b0; acc1[r] = b1; }
    const float* Ap = A + (size_t)r0 * HD;
    for (int k4 = 0; k4 < HD / 4; ++k4) {
        float4 a[8];
#pragma unroll
        for (int r = 0; r < 8; ++r)
            a[r] = *reinterpret_cast<const float4*>(Ap + r * HD + k4 * 4);
#pragma unroll
        for (int j = 0; j < 4; ++j) {
            const int k = k4 * 4 + j;
            const float w0 = W[k * HD + c0];
            const float w1 = W[k * HD + c1];
#pragma unroll
            for (int r = 0; r < 8; ++r) {
                const float av = (j == 0) ? a[r].x : (j == 1) ? a[r].y
                               : (j == 2) ? a[r].z : a[r].w;
                acc0[r] = fmaf(av, w0, acc0[r]);
                acc1[r] = fmaf(av, w1, acc1[r]);
            }
        }
    }
#pragma unroll
    for (int r = 0; r < 8; ++r) {
        out[(size_t)(r0 + r) * HD + c0] = fmaxf(acc0[r], 0.f);
        out[(size_t)(r0 + r) * HD + c1] = fmaxf(acc1[r], 0.f);
    }
}

// ---------------- final head: logits + log_softmax ----------------
__global__ void k_head(const float* __restrict__ z, const float* __restrict__ Wl2,
                       const float* __restrict__ bl2, float* __restrict__ out0) {
    int g = blockIdx.x * blockDim.x + threadIdx.x;
    if (g >= NG) return;
    float l[NC];
#pragma unroll
    for (int c = 0; c < NC; ++c) l[c] = bl2[c];
    for (int k = 0; k < HD; ++k) {
        float zv = z[(size_t)g * HD + k];
#pragma unroll
        for (int c = 0; c < NC; ++c) l[c] = fmaf(zv, Wl2[k * NC + c], l[c]);
    }
    float m = l[0];
#pragma unroll
    for (int c = 1; c < NC; ++c) m = fmaxf(m, l[c]);
    float sum = 0.f;
#pragma unroll
    for (int c = 0; c < NC; ++c) sum += expf(l[c] - m);
    float lse = m + logf(sum);
#pragma unroll
    for (int c = 0; c < NC; ++c) out0[g * NC + c] = l[c] - lse;
}

extern "C" void kernel_launch(void* const* d_in, const int* in_sizes, int n_in,
                              void* d_out, int out_size, void* d_ws, size_t ws_size,
                              hipStream_t stream) {
    const float* x   = (const float*)d_in[0];
    const int*   ei  = (const int*)d_in[1];
    const int*   src = ei;
    const int*   dst = ei + NE;
    const int*   batch = (const int*)d_in[2];
    const float* W1l = (const float*)d_in[4];
    const float* b1l = (const float*)d_in[5];
    const float* W1r = (const float*)d_in[6];
    const float* W2l = (const float*)d_in[7];
    const float* b2l = (const float*)d_in[8];
    const float* W2r = (const float*)d_in[9];
    const float* Wc1 = (const float*)d_in[10];
    const float* bc1 = (const float*)d_in[11];
    const float* Wc2 = (const float*)d_in[12];
    const float* bc2 = (const float*)d_in[13];
    const float* Wl1 = (const float*)d_in[14];
    const float* bl1 = (const float*)d_in[15];
    const float* Wl2 = (const float*)d_in[16];
    const float* bl2 = (const float*)d_in[17];

    char* ws = (char*)d_ws;
    const size_t BB = (size_t)NN * HD * 2;  // 25,600,000 (bf16 buffer)
    unsigned short* xb   = (unsigned short*)(ws);
    unsigned short* bufA = (unsigned short*)(ws + BB);
    unsigned short* bufB = (unsigned short*)(ws + 2 * BB);
    size_t O = 3 * BB;  // 76,800,000
    int*   cnt     = (int*)(ws + O);
    int*   excl    = (int*)(ws + O + 400000);
    int*   row_off = (int*)(ws + O + 800000);
    int*   fillp   = (int*)(ws + O + 1200064);
    int*   csr     = (int*)(ws + O + 1600064);
    int*   bsum    = (int*)(ws + O + 4160064);
    float* a2      = (float*)(ws + O + 4164160);
    float* adj     = (float*)(ws + O + 4964160);
    float* csum    = (float*)(ws + O + 4972352);
    float* zbuf    = (float*)(ws + O + 4972864);
    unsigned short* w1lt = (unsigned short*)(ws + O + 5235008);
    unsigned short* w1rt = w1lt + 16384;
    unsigned short* w2lt = w1rt + 16384;
    unsigned short* w2rt = w2lt + 16384;
    unsigned short* wc1t = w2rt + 16384;

    float* out0 = (float*)d_out;     // 512*6
    float* pos  = out0 + NG * NC;    // 512*128
    float* gemb = pos + NG * HD;     // 512*128
    float* pen  = gemb + NG * HD;    // 1

    hipMemsetAsync(cnt, 0, NN * 4, stream);
    hipMemsetAsync(fillp, 0, NN * 4, stream);
    hipMemsetAsync(adj, 0, NG * 4 * 4, stream);
    hipMemsetAsync(csum, 0, HD * 4, stream);

    // conversions
    k_cvt<<<6250, 256, 0, stream>>>(x, xb, NN * HD / 8);
    k_prepw<<<64, 256, 0, stream>>>(W1l, w1lt);
    k_prepw<<<64, 256, 0, stream>>>(W1r, w1rt);
    k_prepw<<<64, 256, 0, stream>>>(W2l, w2lt);
    k_prepw<<<64, 256, 0, stream>>>(W2r, w2rt);
    k_prepw<<<64, 256, 0, stream>>>(Wc1, wc1t);

    // CSR build (by dst)
    k_count<<<NE / 256, 256, 0, stream>>>(dst, cnt);
    k_scan1<<<391, 256, 0, stream>>>(cnt, excl, bsum, NN);
    k_scan2<<<1, 512, 0, stream>>>(bsum, 391);
    k_scan3<<<391, 256, 0, stream>>>(excl, bsum, row_off, NN);
    k_fill<<<NE / 256, 256, 0, stream>>>(src, dst, row_off, fillp, csr);

    const int GEMM_GRID = (NN + 127) / 128;  // 782 (128 rows/block)
    // Layer 1: h1 = relu(mean@W1l + xb@W1r + b1l) -> bufB
    k_gather_b<<<NN / 4, 256, 0, stream>>>(xb, row_off, csr, bufA);
    mfma_dual<<<GEMM_GRID, 256, 0, stream>>>(bufA, w1lt, xb, w1rt, b1l, bufB, NN);
    // Layer 2: h2 = relu(mean@W2l + h1@W2r + b2l) -> xb
    k_gather_b<<<NN / 4, 256, 0, stream>>>(bufB, row_off, csr, bufA);
    mfma_dual<<<GEMM_GRID, 256, 0, stream>>>(bufA, w2lt, bufB, w2rt, b2l, xb, NN);
    // fused: a = softmax(tanh(h2@Wc1+bc1)@Wc2 + bc2)
    mfma_attn<<<GEMM_GRID, 256, 0, stream>>>(xb, wc1t, bc1, Wc2, bc2, a2, NN);
    // pos + colsum fused
    k_pos<<<NG, 512, 0, stream>>>(xb, a2, batch, pos, csum);
    // graph_emb
    k_gemb<<<NG * HD / 256, 256, 0, stream>>>(csum, gemb);
    // new_adj + penalty
    k_adj<<<120, 256, 0, stream>>>(src, dst, batch, a2, adj);
    k_penalty<<<1, 512, 0, stream>>>(adj, pen);
    // head
    gemm_head<<<NG / 32, 256, 0, stream>>>(pos, Wl1, bl1, zbuf, NG);
    k_head<<<2, 256, 0, stream>>>(zbuf, Wl2, bl2, out0);
}

// Round 6
// 336.368 us; speedup vs baseline: 2.8199x; 1.0006x over previous
//
#include <hip/hip_runtime.h>

#define NN 100000
#define NE 640000
#define HD 128
#define NG 512
#define NC 6
#define EPSV 1e-5f

typedef __bf16 bf16_t;
typedef bf16_t bf16x8 __attribute__((ext_vector_type(8)));
typedef float f32x4 __attribute__((ext_vector_type(4)));

__device__ __forceinline__ float b2f(unsigned int u16) {
    return __builtin_bit_cast(float, u16 << 16);
}
__device__ __forceinline__ unsigned short f2b(float f) {
    unsigned int u = __builtin_bit_cast(unsigned int, f);
    unsigned int r = (u + 0x7fffu + ((u >> 16) & 1u)) >> 16;
    return (unsigned short)r;
}

// ---------------- fp32 -> bf16 conversion (x) ----------------
__global__ __launch_bounds__(256) void k_cvt(const float* __restrict__ in,
                                             unsigned short* __restrict__ out, int n8) {
    int i = blockIdx.x * 256 + threadIdx.x;
    if (i >= n8) return;
    float4 v0 = reinterpret_cast<const float4*>(in)[i * 2];
    float4 v1 = reinterpret_cast<const float4*>(in)[i * 2 + 1];
    unsigned short u[8] = {f2b(v0.x), f2b(v0.y), f2b(v0.z), f2b(v0.w),
                           f2b(v1.x), f2b(v1.y), f2b(v1.z), f2b(v1.w)};
    reinterpret_cast<uint4*>(out)[i] = *reinterpret_cast<uint4*>(u);
}

// ---------------- all 5 weight transposes in one launch ----------------
__global__ __launch_bounds__(256) void k_prepw_all(
    const float* __restrict__ Wa, const float* __restrict__ Wb,
    const float* __restrict__ Wc, const float* __restrict__ Wd,
    const float* __restrict__ We, unsigned short* __restrict__ Wt) {
    int i = blockIdx.x * 256 + threadIdx.x;  // 5*16384
    int w = i >> 14, r = i & 16383;
    int k = r >> 7, n = r & 127;
    const float* W = (w == 0) ? Wa : (w == 1) ? Wb : (w == 2) ? Wc : (w == 3) ? Wd : We;
    Wt[w * 16384 + n * HD + k] = f2b(W[k * HD + n]);
}

// ---------------- counting / CSR build ----------------
__global__ void k_count(const int* __restrict__ dst, int* __restrict__ cnt) {
    int e = blockIdx.x * blockDim.x + threadIdx.x;
    if (e < NE) atomicAdd(&cnt[dst[e]], 1);
}

__global__ void k_scan1(const int* __restrict__ cnt, int* __restrict__ excl,
                        int* __restrict__ bsum, int n) {
    __shared__ int sh[256];
    int i = blockIdx.x * 256 + threadIdx.x;
    int v = (i < n) ? cnt[i] : 0;
    sh[threadIdx.x] = v;
    __syncthreads();
    for (int off = 1; off < 256; off <<= 1) {
        int t = (threadIdx.x >= off) ? sh[threadIdx.x - off] : 0;
        __syncthreads();
        sh[threadIdx.x] += t;
        __syncthreads();
    }
    if (i < n) excl[i] = sh[threadIdx.x] - v;
    if (threadIdx.x == 255) bsum[blockIdx.x] = sh[255];
}

__global__ void k_scan2(int* bsum, int nb) {
    __shared__ int sh[512];
    int t = threadIdx.x;
    sh[t] = (t < nb) ? bsum[t] : 0;
    __syncthreads();
    for (int off = 1; off < 512; off <<= 1) {
        int v = (t >= off) ? sh[t - off] : 0;
        __syncthreads();
        sh[t] += v;
        __syncthreads();
    }
    if (t < nb) bsum[t] = sh[t];
}

__global__ void k_scan3(const int* __restrict__ excl, const int* __restrict__ bsum,
                        int* __restrict__ row_off, int n) {
    int i = blockIdx.x * 256 + threadIdx.x;
    if (i < n) row_off[i] = excl[i] + (blockIdx.x ? bsum[blockIdx.x - 1] : 0);
    if (i == 0) row_off[n] = NE;
}

// count-down fill: slot = row_off[d] + (--cnt[d]); csr written nontemporal
__global__ void k_fill(const int* __restrict__ src, const int* __restrict__ dst,
                       const int* __restrict__ row_off, int* __restrict__ cnt,
                       int* __restrict__ csr) {
    int e = blockIdx.x * blockDim.x + threadIdx.x;
    if (e < NE) {
        int d = dst[e];
        int p = atomicSub(&cnt[d], 1);
        __builtin_nontemporal_store(src[e], &csr[row_off[d] + p - 1]);
    }
}

// ---------------- mean aggregation: 8 neighbors in flight, 16B loads/lane ----------------
__global__ __launch_bounds__(256) void k_gather_b(const unsigned short* __restrict__ X,
                                                  const int* __restrict__ row_off,
                                                  const int* __restrict__ csr,
                                                  unsigned short* __restrict__ out) {
    int node = (blockIdx.x * blockDim.x + threadIdx.x) >> 6;
    int lane = threadIdx.x & 63;
    if (node >= NN) return;
    int beg = row_off[node], end = row_off[node + 1];
    int grp = lane >> 4;
    int sub = lane & 15;
    float accA[8] = {0.f, 0.f, 0.f, 0.f, 0.f, 0.f, 0.f, 0.f};
    float accB[8] = {0.f, 0.f, 0.f, 0.f, 0.f, 0.f, 0.f, 0.f};
    for (int j = beg; j < end; j += 8) {
        int jj0 = j + grp, jj1 = j + 4 + grp;
        bool ok0 = jj0 < end, ok1 = jj1 < end;
        int s0 = csr[ok0 ? jj0 : beg];
        int s1 = csr[ok1 ? jj1 : beg];
        uint4 v0 = *reinterpret_cast<const uint4*>(X + (size_t)s0 * HD + sub * 8);
        uint4 v1 = *reinterpret_cast<const uint4*>(X + (size_t)s1 * HD + sub * 8);
        if (ok0) {
            accA[0] += b2f(v0.x & 0xffffu); accA[1] += b2f(v0.x >> 16);
            accA[2] += b2f(v0.y & 0xffffu); accA[3] += b2f(v0.y >> 16);
            accA[4] += b2f(v0.z & 0xffffu); accA[5] += b2f(v0.z >> 16);
            accA[6] += b2f(v0.w & 0xffffu); accA[7] += b2f(v0.w >> 16);
        }
        if (ok1) {
            accB[0] += b2f(v1.x & 0xffffu); accB[1] += b2f(v1.x >> 16);
            accB[2] += b2f(v1.y & 0xffffu); accB[3] += b2f(v1.y >> 16);
            accB[4] += b2f(v1.z & 0xffffu); accB[5] += b2f(v1.z >> 16);
            accB[6] += b2f(v1.w & 0xffffu); accB[7] += b2f(v1.w >> 16);
        }
    }
#pragma unroll
    for (int k = 0; k < 8; ++k) {
        float a = accA[k] + accB[k];
        a += __shfl_xor(a, 16, 64);
        a += __shfl_xor(a, 32, 64);
        accA[k] = a;
    }
    if (grp == 0) {
        float inv = 1.f / fmaxf((float)(end - beg), 1.f);
        unsigned short u[8];
#pragma unroll
        for (int k = 0; k < 8; ++k) u[k] = f2b(accA[k] * inv);
        *reinterpret_cast<uint4*>(out + (size_t)node * HD + sub * 8) = *reinterpret_cast<uint4*>(u);
    }
}

// ---------------- MFMA dual-source GEMM, LDS-staged weights, 2-phase ----------------
__global__ __launch_bounds__(256) void mfma_dual(
    const unsigned short* __restrict__ A1, const unsigned short* __restrict__ W1t,
    const unsigned short* __restrict__ A2, const unsigned short* __restrict__ W2t,
    const float* __restrict__ bias, unsigned short* __restrict__ out, int M)
{
    __shared__ uint4 wlds[2048];  // 32 KB
    const int wid = threadIdx.x >> 6;
    const int lane = threadIdx.x & 63;
    const int lrow = lane & 15;
    const int lkg = lane >> 4;
    const int r0 = blockIdx.x * 128 + wid * 32;

    bf16x8 a[2][2][4];
#pragma unroll
    for (int s = 0; s < 2; ++s) {
        const unsigned short* Ap = s ? A2 : A1;
#pragma unroll
        for (int g = 0; g < 2; ++g) {
            int row = r0 + g * 16 + lrow;
            row = row < M ? row : M - 1;
            const unsigned short* p = Ap + (size_t)row * HD + lkg * 8;
#pragma unroll
            for (int ks = 0; ks < 4; ++ks)
                a[s][g][ks] = *reinterpret_cast<const bf16x8*>(p + ks * 32);
        }
    }

    f32x4 acc[2][8];
#pragma unroll
    for (int t = 0; t < 8; ++t) {
        float b = bias[t * 16 + lrow];
        acc[0][t] = (f32x4){b, b, b, b};
        acc[1][t] = (f32x4){b, b, b, b};
    }

    const char* ldsb = (const char*)wlds;
#pragma unroll
    for (int s = 0; s < 2; ++s) {
        const uint4* g4 = reinterpret_cast<const uint4*>(s ? W2t : W1t);
        if (s) __syncthreads();
        for (int i = threadIdx.x; i < 2048; i += 256) {
            int di = i ^ ((i >> 4) & 7);
            wlds[di] = g4[i];
        }
        __syncthreads();
#pragma unroll
        for (int ks = 0; ks < 4; ++ks) {
#pragma unroll
            for (int t = 0; t < 8; ++t) {
                int off = (lrow * 256 + lkg * 16 + t * 4096 + ks * 64) ^ ((lrow & 7) << 4);
                bf16x8 b = *reinterpret_cast<const bf16x8*>(ldsb + off);
                acc[0][t] = __builtin_amdgcn_mfma_f32_16x16x32_bf16(a[s][0][ks], b, acc[0][t], 0, 0, 0);
                acc[1][t] = __builtin_amdgcn_mfma_f32_16x16x32_bf16(a[s][1][ks], b, acc[1][t], 0, 0, 0);
            }
        }
    }

#pragma unroll
    for (int g = 0; g < 2; ++g)
#pragma unroll
        for (int t = 0; t < 8; ++t)
#pragma unroll
            for (int r = 0; r < 4; ++r) {
                int row = r0 + g * 16 + lkg * 4 + r;
                if (row < M) {
                    float v = fmaxf(acc[g][t][r], 0.f);
                    out[(size_t)row * HD + t * 16 + lrow] = f2b(v);
                }
            }
}

// ---------------- fused: a2 = softmax(tanh(h@Wc1+bc1) @ Wc2 + bc2), LDS weights ----------------
__global__ __launch_bounds__(256) void mfma_attn(
    const unsigned short* __restrict__ A1, const unsigned short* __restrict__ W1t,
    const float* __restrict__ bias, const float* __restrict__ Wc2,
    const float* __restrict__ bc2, float* __restrict__ a2, int M)
{
    __shared__ uint4 wlds[2048];
    const int wid = threadIdx.x >> 6;
    const int lane = threadIdx.x & 63;
    const int lrow = lane & 15;
    const int lkg = lane >> 4;
    const int r0 = blockIdx.x * 128 + wid * 32;

    bf16x8 a[2][4];
#pragma unroll
    for (int g = 0; g < 2; ++g) {
        int row = r0 + g * 16 + lrow;
        row = row < M ? row : M - 1;
        const unsigned short* p = A1 + (size_t)row * HD + lkg * 8;
#pragma unroll
        for (int ks = 0; ks < 4; ++ks)
            a[g][ks] = *reinterpret_cast<const bf16x8*>(p + ks * 32);
    }

    f32x4 acc[2][8];
#pragma unroll
    for (int t = 0; t < 8; ++t) {
        float b = bias[t * 16 + lrow];
        acc[0][t] = (f32x4){b, b, b, b};
        acc[1][t] = (f32x4){b, b, b, b};
    }

    const uint4* g4 = reinterpret_cast<const uint4*>(W1t);
    for (int i = threadIdx.x; i < 2048; i += 256) {
        int di = i ^ ((i >> 4) & 7);
        wlds[di] = g4[i];
    }
    __syncthreads();

    const char* ldsb = (const char*)wlds;
#pragma unroll
    for (int ks = 0; ks < 4; ++ks) {
#pragma unroll
        for (int t = 0; t < 8; ++t) {
            int off = (lrow * 256 + lkg * 16 + t * 4096 + ks * 64) ^ ((lrow & 7) << 4);
            bf16x8 b = *reinterpret_cast<const bf16x8*>(ldsb + off);
            acc[0][t] = __builtin_amdgcn_mfma_f32_16x16x32_bf16(a[0][ks], b, acc[0][t], 0, 0, 0);
            acc[1][t] = __builtin_amdgcn_mfma_f32_16x16x32_bf16(a[1][ks], b, acc[1][t], 0, 0, 0);
        }
    }

    float p0[2][4] = {{0.f, 0.f, 0.f, 0.f}, {0.f, 0.f, 0.f, 0.f}};
    float p1[2][4] = {{0.f, 0.f, 0.f, 0.f}, {0.f, 0.f, 0.f, 0.f}};
#pragma unroll
    for (int t = 0; t < 8; ++t) {
        float2 wv = reinterpret_cast<const float2*>(Wc2)[t * 16 + lrow];
#pragma unroll
        for (int g = 0; g < 2; ++g)
#pragma unroll
            for (int r = 0; r < 4; ++r) {
                float tv = tanhf(acc[g][t][r]);
                p0[g][r] = fmaf(tv, wv.x, p0[g][r]);
                p1[g][r] = fmaf(tv, wv.y, p1[g][r]);
            }
    }
#pragma unroll
    for (int off = 1; off < 16; off <<= 1) {
#pragma unroll
        for (int g = 0; g < 2; ++g)
#pragma unroll
            for (int r = 0; r < 4; ++r) {
                p0[g][r] += __shfl_xor(p0[g][r], off, 64);
                p1[g][r] += __shfl_xor(p1[g][r], off, 64);
            }
    }
    if (lrow == 0) {
        float B0 = bc2[0], B1 = bc2[1];
#pragma unroll
        for (int g = 0; g < 2; ++g)
#pragma unroll
            for (int r = 0; r < 4; ++r) {
                int row = r0 + g * 16 + lkg * 4 + r;
                if (row < M) {
                    float u0 = p0[g][r] + B0, u1 = p1[g][r] + B1;
                    float m = fmaxf(u0, u1);
                    float e0 = expf(u0 - m), e1 = expf(u1 - m);
                    float inv = 1.f / (e0 + e1);
                    reinterpret_cast<float2*>(a2)[row] = (float2){e0 * inv, e1 * inv};
                }
            }
    }
}

// ---------------- pos + colsum fused ----------------
__global__ __launch_bounds__(512) void k_pos(const unsigned short* __restrict__ h,
                                             const float* __restrict__ a2,
                                             const int* __restrict__ batch,
                                             float* __restrict__ pos_out,
                                             float* __restrict__ csum) {
    __shared__ float4 sh[8][64];
    int g = blockIdx.x;
    int lo = 0, hi = NN;
    while (lo < hi) { int m = (lo + hi) >> 1; if (batch[m] < g) lo = m + 1; else hi = m; }
    int beg = lo;
    hi = NN;
    while (lo < hi) { int m = (lo + hi) >> 1; if (batch[m] < g + 1) lo = m + 1; else hi = m; }
    int end = lo;
    int grp = threadIdx.x >> 6;
    int lane = threadIdx.x & 63;
    float4 acc = {0.f, 0.f, 0.f, 0.f};
    for (int i = beg + grp; i < end; i += 8) {
        float a = a2[i * 2];
        unsigned int v = *reinterpret_cast<const unsigned int*>(h + (size_t)i * HD + lane * 2);
        float f0 = b2f(v & 0xffffu), f1 = b2f(v >> 16);
        acc.x = fmaf(a, f0, acc.x);
        acc.y = fmaf(a, f1, acc.y);
        acc.z += f0;
        acc.w += f1;
    }
    sh[grp][lane] = acc;
    __syncthreads();
    if (threadIdx.x < 64) {
        float4 s = sh[0][lane];
#pragma unroll
        for (int k = 1; k < 8; ++k) {
            float4 t = sh[k][lane];
            s.x += t.x; s.y += t.y; s.z += t.z; s.w += t.w;
        }
        reinterpret_cast<float2*>(pos_out)[g * 64 + lane] = (float2){s.x, s.y};
        atomicAdd(&csum[lane * 2], s.z);
        atomicAdd(&csum[lane * 2 + 1], s.w);
    }
}

__global__ void k_gemb(const float* __restrict__ csum, float* __restrict__ out) {
    int i = blockIdx.x * 256 + threadIdx.x;  // 65536
    out[i] = csum[i & 127] * (1.f / (float)NN);
}

// ---------------- new_adj accumulation: LDS-staged atomics ----------------
__global__ __launch_bounds__(256) void k_adj(const int* __restrict__ src, const int* __restrict__ dst,
                                             const int* __restrict__ batch, const float* __restrict__ a2,
                                             float* __restrict__ adj) {
    __shared__ float sh[NG * 4];  // 8 KB
    for (int i = threadIdx.x; i < NG * 4; i += 256) sh[i] = 0.f;
    __syncthreads();
    for (int e = blockIdx.x * 256 + threadIdx.x; e < NE; e += gridDim.x * 256) {
        int s = src[e], d = dst[e];
        int bs = batch[s], bd = batch[d];
        if (bs != bd) continue;
        float a0s = a2[2 * s], a1s = a2[2 * s + 1];
        float a0d = a2[2 * d], a1d = a2[2 * d + 1];
        float* A = sh + bs * 4;
        atomicAdd(A + 0, a0s * a0d);
        atomicAdd(A + 1, a0s * a1d);
        atomicAdd(A + 2, a1s * a0d);
        atomicAdd(A + 3, a1s * a1d);
    }
    __syncthreads();
    for (int i = threadIdx.x; i < NG * 4; i += 256) {
        float v = sh[i];
        if (v != 0.f) atomicAdd(&adj[i], v);
    }
}

__global__ void k_penalty(const float* __restrict__ adj, float* __restrict__ out) {
    __shared__ float sh[512];
    int g = threadIdx.x;
    float x0 = adj[g * 4], x1 = adj[g * 4 + 1], x2 = adj[g * 4 + 2], x3 = adj[g * 4 + 3];
    float l0 = fabsf(x0) + fabsf(x1);
    float l1 = fabsf(x2) + fabsf(x3);
    float d0 = x0 / fmaxf(l0, EPSV);
    float d1 = x3 / fmaxf(l1, EPSV);
    sh[g] = 0.5f * ((d0 - 1.f) * (d0 - 1.f) + (d1 - 1.f) * (d1 - 1.f));
    __syncthreads();
    for (int off = 256; off >= 1; off >>= 1) {
        if (g < off) sh[g] += sh[g + off];
        __syncthreads();
    }
    if (g == 0) out[0] = sh[0] * (1.f / (float)NG);
}

// ---------------- fp32 head GEMM (512 rows): out = relu(A@W + b) ----------------
__global__ __launch_bounds__(256) void gemm_head(
    const float* __restrict__ A, const float* __restrict__ W,
    const float* __restrict__ bias, float* __restrict__ out, int M)
{
    const int tid = threadIdx.x;
    const int w = __builtin_amdgcn_readfirstlane(tid >> 6);
    const int lane = tid & 63;
    const int r0 = blockIdx.x * 32 + w * 8;
    if (r0 >= M) return;
    const int c0 = lane, c1 = lane + 64;
    float acc0[8], acc1[8];
    const float b0 = bias[c0], b1 = bias[c1];
#pragma unroll
    for (int r = 0; r < 8; ++r) { acc0[r] = b0; acc1[r] = b1; }
    const float* Ap = A + (size_t)r0 * HD;
    for (int k4 = 0; k4 < HD / 4; ++k4) {
        float4 a[8];
#pragma unroll
        for (int r = 0; r < 8; ++r)
            a[r] = *reinterpret_cast<const float4*>(Ap + r * HD + k4 * 4);
#pragma unroll
        for (int j = 0; j < 4; ++j) {
            const int k = k4 * 4 + j;
            const float w0 = W[k * HD + c0];
            const float w1 = W[k * HD + c1];
#pragma unroll
            for (int r = 0; r < 8; ++r) {
                const float av = (j == 0) ? a[r].x : (j == 1) ? a[r].y
                               : (j == 2) ? a[r].z : a[r].w;
                acc0[r] = fmaf(av, w0, acc0[r]);
                acc1[r] = fmaf(av, w1, acc1[r]);
            }
        }
    }
#pragma unroll
    for (int r = 0; r < 8; ++r) {
        out[(size_t)(r0 + r) * HD + c0] = fmaxf(acc0[r], 0.f);
        out[(size_t)(r0 + r) * HD + c1] = fmaxf(acc1[r], 0.f);
    }
}

// ---------------- final head: logits + log_softmax ----------------
__global__ void k_head(const float* __restrict__ z, const float* __restrict__ Wl2,
                       const float* __restrict__ bl2, float* __restrict__ out0) {
    int g = blockIdx.x * blockDim.x + threadIdx.x;
    if (g >= NG) return;
    float l[NC];
#pragma unroll
    for (int c = 0; c < NC; ++c) l[c] = bl2[c];
    for (int k = 0; k < HD; ++k) {
        float zv = z[(size_t)g * HD + k];
#pragma unroll
        for (int c = 0; c < NC; ++c) l[c] = fmaf(zv, Wl2[k * NC + c], l[c]);
    }
    float m = l[0];
#pragma unroll
    for (int c = 1; c < NC; ++c) m = fmaxf(m, l[c]);
    float sum = 0.f;
#pragma unroll
    for (int c = 0; c < NC; ++c) sum += expf(l[c] - m);
    float lse = m + logf(sum);
#pragma unroll
    for (int c = 0; c < NC; ++c) out0[g * NC + c] = l[c] - lse;
}

extern "C" void kernel_launch(void* const* d_in, const int* in_sizes, int n_in,
                              void* d_out, int out_size, void* d_ws, size_t ws_size,
                              hipStream_t stream) {
    const float* x   = (const float*)d_in[0];
    const int*   ei  = (const int*)d_in[1];
    const int*   src = ei;
    const int*   dst = ei + NE;
    const int*   batch = (const int*)d_in[2];
    const float* W1l = (const float*)d_in[4];
    const float* b1l = (const float*)d_in[5];
    const float* W1r = (const float*)d_in[6];
    const float* W2l = (const float*)d_in[7];
    const float* b2l = (const float*)d_in[8];
    const float* W2r = (const float*)d_in[9];
    const float* Wc1 = (const float*)d_in[10];
    const float* bc1 = (const float*)d_in[11];
    const float* Wc2 = (const float*)d_in[12];
    const float* bc2 = (const float*)d_in[13];
    const float* Wl1 = (const float*)d_in[14];
    const float* bl1 = (const float*)d_in[15];
    const float* Wl2 = (const float*)d_in[16];
    const float* bl2 = (const float*)d_in[17];

    char* ws = (char*)d_ws;
    const size_t BB = (size_t)NN * HD * 2;  // 25,600,000 (bf16 buffer)
    unsigned short* xb   = (unsigned short*)(ws);
    unsigned short* bufA = (unsigned short*)(ws + BB);
    unsigned short* bufB = (unsigned short*)(ws + 2 * BB);
    size_t O = 3 * BB;  // 76,800,000
    // zeroed region (single memset): cnt | adj | csum
    int*   cnt     = (int*)(ws + O);                 // 400000 B
    float* adj     = (float*)(ws + O + 400000);      // 8192 B
    float* csum    = (float*)(ws + O + 408192);      // 512 B
    // non-zeroed scratch
    int*   excl    = (int*)(ws + O + 408704);        // 400000 B
    int*   row_off = (int*)(ws + O + 808704);        // 400064 B
    int*   csr     = (int*)(ws + O + 1208768);       // 2560000 B
    int*   bsum    = (int*)(ws + O + 3768768);       // 4096 B
    float* a2      = (float*)(ws + O + 3772864);     // 800000 B
    float* zbuf    = (float*)(ws + O + 4572864);     // 262144 B
    unsigned short* w1lt = (unsigned short*)(ws + O + 4835008);  // 5*32768 B
    unsigned short* w1rt = w1lt + 16384;
    unsigned short* w2lt = w1rt + 16384;
    unsigned short* w2rt = w2lt + 16384;
    unsigned short* wc1t = w2rt + 16384;

    float* out0 = (float*)d_out;     // 512*6
    float* pos  = out0 + NG * NC;    // 512*128
    float* gemb = pos + NG * HD;     // 512*128
    float* pen  = gemb + NG * HD;    // 1

    hipMemsetAsync(ws + O, 0, 408704, stream);  // cnt+adj+csum

    // conversions
    k_cvt<<<6250, 256, 0, stream>>>(x, xb, NN * HD / 8);
    k_prepw_all<<<320, 256, 0, stream>>>(W1l, W1r, W2l, W2r, Wc1, w1lt);

    // CSR build (by dst); k_fill consumes cnt via count-down
    k_count<<<NE / 256, 256, 0, stream>>>(dst, cnt);
    k_scan1<<<391, 256, 0, stream>>>(cnt, excl, bsum, NN);
    k_scan2<<<1, 512, 0, stream>>>(bsum, 391);
    k_scan3<<<391, 256, 0, stream>>>(excl, bsum, row_off, NN);
    k_fill<<<NE / 256, 256, 0, stream>>>(src, dst, row_off, cnt, csr);

    const int GEMM_GRID = (NN + 127) / 128;  // 782
    // Layer 1: h1 = relu(mean@W1l + xb@W1r + b1l) -> bufB
    k_gather_b<<<NN / 4, 256, 0, stream>>>(xb, row_off, csr, bufA);
    mfma_dual<<<GEMM_GRID, 256, 0, stream>>>(bufA, w1lt, xb, w1rt, b1l, bufB, NN);
    // Layer 2: h2 = relu(mean@W2l + h1@W2r + b2l) -> xb
    k_gather_b<<<NN / 4, 256, 0, stream>>>(bufB, row_off, csr, bufA);
    mfma_dual<<<GEMM_GRID, 256, 0, stream>>>(bufA, w2lt, bufB, w2rt, b2l, xb, NN);
    // fused: a = softmax(tanh(h2@Wc1+bc1)@Wc2 + bc2)
    mfma_attn<<<GEMM_GRID, 256, 0, stream>>>(xb, wc1t, bc1, Wc2, bc2, a2, NN);
    // pos + colsum fused
    k_pos<<<NG, 512, 0, stream>>>(xb, a2, batch, pos, csum);
    // graph_emb
    k_gemb<<<NG * HD / 256, 256, 0, stream>>>(csum, gemb);
    // new_adj + penalty
    k_adj<<<120, 256, 0, stream>>>(src, dst, batch, a2, adj);
    k_penalty<<<1, 512, 0, stream>>>(adj, pen);
    // head
    gemm_head<<<NG / 32, 256, 0, stream>>>(pos, Wl1, bl1, zbuf, NG);
    k_head<<<2, 256, 0, stream>>>(zbuf, Wl2, bl2, out0);
}